// Round 11
// baseline (120.673 us; speedup 1.0000x reference)
//
#include <hip/hip_runtime.h>
#include <hip/hip_bf16.h>
#include <math.h>

#define H_  12
#define N_  1620
#define D_  64
#define C_  768
#define NS_ 20
#define V_  4
#define P_  400

#define TPP    64
#define PTILES 7    // ceil(400/64)
#define SPL    26   // spatial key splits of 64
#define NPANO  672  // pano partial blocks
#define NPART  (NPANO + SPL * H_)   // 984 total partial slots

typedef __bf16 bf16x8 __attribute__((ext_vector_type(8)));
typedef float f32x4 __attribute__((ext_vector_type(4)));
typedef unsigned short ushort8 __attribute__((ext_vector_type(8)));
typedef unsigned short ushort4v __attribute__((ext_vector_type(4)));
typedef unsigned int uint4v __attribute__((ext_vector_type(4)));
typedef unsigned int uint2v __attribute__((ext_vector_type(2)));

struct HL { unsigned short h, l; };

__device__ __forceinline__ unsigned short bf16_rne(float v) {
    unsigned int u = __builtin_bit_cast(unsigned int, v);
    return (unsigned short)((u + 0x7fffu + ((u >> 16) & 1u)) >> 16);
}
__device__ __forceinline__ HL split2(float v) {
    HL r;
    r.h = bf16_rne(v);
    float hf = __builtin_bit_cast(float, (unsigned int)r.h << 16);
    r.l = bf16_rne(v - hf);
    return r;
}
__device__ __forceinline__ float unpk(unsigned int u) {
    return __builtin_bit_cast(float, u & 0xffff0000u) + __builtin_bit_cast(float, u << 16);
}
__device__ __forceinline__ void unpack8(uint4v a, uint4v b, bf16x8& hi, bf16x8& lo) {
    ushort8 ea = __builtin_bit_cast(ushort8, a);
    ushort8 eb = __builtin_bit_cast(ushort8, b);
    hi = __builtin_bit_cast(bf16x8, __builtin_shufflevector(ea, eb, 1,3,5,7,9,11,13,15));
    lo = __builtin_bit_cast(bf16x8, __builtin_shufflevector(ea, eb, 0,2,4,6,8,10,12,14));
}
// split 4 packed u32 (hi<<16|lo) into hi-pair/lo-pair u32s (ushort4 each)
__device__ __forceinline__ void split_u32x4(uint4v kv, uint2v& hv, uint2v& lv) {
    hv.x = (kv.x >> 16) | (kv.y & 0xffff0000u);
    hv.y = (kv.z >> 16) | (kv.w & 0xffff0000u);
    lv.x = (kv.x & 0xffffu) | (kv.y << 16);
    lv.y = (kv.z & 0xffffu) | (kv.w << 16);
}
// bijective XCD-chunked swizzle (m204)
__device__ __forceinline__ int xcd_swz(int orig, int nwg) {
    int q = nwg >> 3, r = nwg & 7;
    int x = orig & 7, p = orig >> 3;
    return (x < r ? x * (q + 1) : r * (q + 1) + (x - r) * q) + p;
}
__device__ __forceinline__ void gload16(const void* g, void* l) {
    __builtin_amdgcn_global_load_lds((const __attribute__((address_space(1))) void*)g,
                                     (__attribute__((address_space(3))) void*)l, 16, 0, 0);
}

// ---------------------------------------------------------------------------
#define N4_X  ((N_ * C_) / 4)
#define N4_W  ((3 * C_ * C_) / 4)
#define N4_PW ((C_ * C_) / 4)

__global__ __launch_bounds__(256)
void split_all(const float* __restrict__ x, const float* __restrict__ w,
               const float* __restrict__ pw,
               unsigned short* __restrict__ xhi, unsigned short* __restrict__ xlo,
               unsigned short* __restrict__ whi, unsigned short* __restrict__ wlo,
               unsigned short* __restrict__ pwhi, unsigned short* __restrict__ pwlo)
{
    int i = blockIdx.x * 256 + threadIdx.x;
    const float* src; unsigned short* dh; unsigned short* dl; int idx;
    if (i < N4_X)                { src = x;  dh = xhi;  dl = xlo;  idx = i; }
    else if (i < N4_X + N4_W)    { src = w;  dh = whi;  dl = wlo;  idx = i - N4_X; }
    else if (i < N4_X + N4_W + N4_PW) { src = pw; dh = pwhi; dl = pwlo; idx = i - N4_X - N4_W; }
    else return;
    float4 v = ((const float4*)src)[idx];
    HL a = split2(v.x), b = split2(v.y), c = split2(v.z), d = split2(v.w);
    ushort4v h, l;
    h.x = a.h; h.y = b.h; h.z = c.h; h.w = d.h;
    l.x = a.l; l.y = b.l; l.z = c.l; l.w = d.l;
    ((ushort4v*)dh)[idx] = h;
    ((ushort4v*)dl)[idx] = l;
}

// ---------------------------------------------------------------------------
// MFMA NT GEMM, split-2 bf16. Tile 128(M) x 64(N), BK=32, 4 waves (2x2).
// Staging via global_load_lds width=16.
// ---------------------------------------------------------------------------
template<int MODE>
__global__ __launch_bounds__(256)
void gemm_mfma(const unsigned short* __restrict__ Ah, const unsigned short* __restrict__ Al,
               const unsigned short* __restrict__ Bh, const unsigned short* __restrict__ Bl,
               const float* __restrict__ bias, int M, int N,
               float* __restrict__ out0, float* __restrict__ out1, float* __restrict__ out2)
{
    __shared__ unsigned short Ash[2][128 * 32];
    __shared__ unsigned short Bsh[2][64 * 32];
    const int tid = threadIdx.x;
    const int lane = tid & 63;
    const int w = tid >> 6;

    const int wg = xcd_swz(blockIdx.x, gridDim.x);
    const int tmc = (M + 127) >> 7;
    const int tm = (wg % tmc) * 128;
    const int tn = (wg / tmc) * 64;

    const int wm = (w >> 1) * 64;
    const int wn = (w & 1) * 32;

    f32x4 acc[4][2] = {};

    const int lrow = lane >> 2;
    const int lcol = (lane & 3) * 8;

    for (int k0 = 0; k0 < 768; k0 += 32) {
        #pragma unroll
        for (int t = 0; t < 2; ++t) {
            int row = w * 32 + t * 16 + lrow;
            int gmA = tm + row; if (gmA > M - 1) gmA = M - 1;
            gload16(Ah + (size_t)gmA * 768 + k0 + lcol, &Ash[0][(w * 2 + t) * 512]);
            gload16(Al + (size_t)gmA * 768 + k0 + lcol, &Ash[1][(w * 2 + t) * 512]);
        }
        {
            int gnB = tn + w * 16 + lrow;
            gload16(Bh + (size_t)gnB * 768 + k0 + lcol, &Bsh[0][w * 512]);
            gload16(Bl + (size_t)gnB * 768 + k0 + lcol, &Bsh[1][w * 512]);
        }
        __syncthreads();

        const int fr = lane & 15;
        const int fk = (lane >> 4) * 8;
        bf16x8 ah[4], al[4], bh[2], bl[2];
        #pragma unroll
        for (int i = 0; i < 4; ++i) {
            ah[i] = *(const bf16x8*)&Ash[0][(wm + i * 16 + fr) * 32 + fk];
            al[i] = *(const bf16x8*)&Ash[1][(wm + i * 16 + fr) * 32 + fk];
        }
        #pragma unroll
        for (int i = 0; i < 2; ++i) {
            bh[i] = *(const bf16x8*)&Bsh[0][(wn + i * 16 + fr) * 32 + fk];
            bl[i] = *(const bf16x8*)&Bsh[1][(wn + i * 16 + fr) * 32 + fk];
        }
        #pragma unroll
        for (int mi = 0; mi < 4; ++mi)
            #pragma unroll
            for (int ni = 0; ni < 2; ++ni) {
                acc[mi][ni] = __builtin_amdgcn_mfma_f32_16x16x32_bf16(ah[mi], bh[ni], acc[mi][ni], 0, 0, 0);
                acc[mi][ni] = __builtin_amdgcn_mfma_f32_16x16x32_bf16(ah[mi], bl[ni], acc[mi][ni], 0, 0, 0);
                acc[mi][ni] = __builtin_amdgcn_mfma_f32_16x16x32_bf16(al[mi], bh[ni], acc[mi][ni], 0, 0, 0);
            }
        __syncthreads();
    }

    const int fr = lane & 15;
    const int fq = (lane >> 4) * 4;
    #pragma unroll
    for (int mi = 0; mi < 4; ++mi) {
        #pragma unroll
        for (int ni = 0; ni < 2; ++ni) {
            int n = tn + wn + ni * 16 + fr;
            float bb = bias[n];
            #pragma unroll
            for (int r = 0; r < 4; ++r) {
                int m = tm + wm + mi * 16 + fq + r;
                if (m >= M) continue;
                float val = acc[mi][ni][r] + bb;
                if (MODE == 0) {
                    out0[(size_t)m * N + n] = val;
                } else {
                    int which = n / C_;
                    int rr = n - which * C_;
                    int h = rr >> 6, d = rr & 63;
                    float* dst = (which == 0) ? out0 : (which == 1) ? out1 : out2;
                    HL hl2 = split2(val);
                    ((unsigned int*)dst)[((size_t)h * N_ + m) * D_ + d] =
                        ((unsigned int)hl2.h << 16) | hl2.l;
                }
            }
        }
    }
}

// ---------------------------------------------------------------------------
// Unified attention partials (MFMA flash, hi/lo LDS planes, 32 KB).
// Blocks [0,672): pano split-K (XCD swizzled). Blocks [672,984): spatial.
// Each block: 64-row Q tile x chunks [ch_lo,ch_hi) of 64 keys; writes
// packed-bf16-pair o partials + m + l into slot `slot`.
// ---------------------------------------------------------------------------
__global__ __launch_bounds__(256)
void attn_fused(const unsigned int* __restrict__ qp, const unsigned int* __restrict__ kp,
                const unsigned int* __restrict__ vp,
                unsigned int* __restrict__ po, float* __restrict__ pm, float* __restrict__ pl)
{
    __shared__ unsigned short KH[64][64];
    __shared__ unsigned short KLo[64][64];
    __shared__ unsigned short VH[64][64];
    __shared__ unsigned short VLo[64][64];

    const int tid = threadIdx.x;
    const int lane = tid & 63;
    const int w = tid >> 6;
    const int wr = w * 16;
    const int c = lane & 15;
    const int g = lane >> 4;

    const bool is_pano = (blockIdx.x < NPANO);
    int h, vw = 0, p0 = 0, cv = 0, n0 = 0, ch_lo, ch_hi, slot;
    if (is_pano) {
        int wg = xcd_swz(blockIdx.x, NPANO);
        int half = wg & 1;
        int t = wg >> 1;
        int pt = t % PTILES;
        int t2 = t / PTILES;
        vw = t2 & 3;
        h  = t2 >> 2;
        p0 = pt * TPP;
        cv = (vw + 1) & 3;
        ch_lo = half ? 5 : 0;
        ch_hi = half ? 9 : 5;
        slot = wg;
    } else {
        int id = blockIdx.x - NPANO;
        int sp = id % SPL;
        h = id / SPL;
        n0 = sp * 64;
        ch_lo = 0; ch_hi = 1;
        slot = NPANO + id;
    }

    // ---- persistent Q A-frags ----
    bf16x8 qh[2], ql[2];
    {
        int rowq;
        if (is_pano) { rowq = NS_ + vw * P_ + p0 + wr + c; if (rowq > N_ - 1) rowq = N_ - 1; }
        else         { rowq = wr + c; if (rowq > NS_ - 1) rowq = NS_ - 1; }
        const unsigned int* qrow = qp + (((size_t)h * N_ + rowq) << 6);
        #pragma unroll
        for (int ss = 0; ss < 2; ++ss) {
            uint4v u0 = *(const uint4v*)(qrow + ss * 32 + g * 8);
            uint4v u1 = *(const uint4v*)(qrow + ss * 32 + g * 8 + 4);
            unpack8(u0, u1, qh[ss], ql[ss]);
        }
    }

    float m[4], l[4];
    f32x4 o[4] = {};
    #pragma unroll
    for (int r = 0; r < 4; ++r) { m[r] = -INFINITY; l[r] = 0.f; }

    for (int ch = ch_lo; ch < ch_hi; ++ch) {
        // ---- stage K into hi/lo planes, swizzled ----
        #pragma unroll
        for (int i = 0; i < 4; ++i) {
            int f = i * 256 + tid;
            int key = f >> 4, dq = (f & 15) << 2;
            int n;
            if (!is_pano) {
                n = n0 + key; if (n > N_ - 1) n = N_ - 1;
            } else if (ch < 7) {
                int sj = ch * 64 + key;
                n = (sj < NS_) ? sj : (NS_ + vw * P_ + (sj - NS_));
                if (sj >= NS_ + P_) n = 0;
            } else {
                int pp = p0 + (ch - 7) * 64 + key;
                if (pp >= P_) pp -= P_;
                if (pp >= P_) pp -= P_;
                n = NS_ + cv * P_ + pp;
            }
            uint4v kv = *(const uint4v*)(kp + (((size_t)h * N_ + n) << 6) + dq);
            uint2v hv, lv;
            split_u32x4(kv, hv, lv);
            int dx = dq ^ ((key & 7) << 3);
            *(uint2v*)&KH[key][dx]  = hv;
            *(uint2v*)&KLo[key][dx] = lv;
        }
        // ---- stage V transposed into hi/lo planes ----
        {
            int kg = (tid & 15) << 2;
            int dq = (tid >> 4) << 2;
            uint4v rr[4];
            #pragma unroll
            for (int tt = 0; tt < 4; ++tt) {
                int key = kg + tt;
                int n;
                if (!is_pano) {
                    n = n0 + key; if (n > N_ - 1) n = N_ - 1;
                } else if (ch < 7) {
                    int sj = ch * 64 + key;
                    n = (sj < NS_) ? sj : (NS_ + vw * P_ + (sj - NS_));
                    if (sj >= NS_ + P_) n = 0;
                } else {
                    int pp = p0 + (ch - 7) * 64 + key;
                    if (pp >= P_) pp -= P_;
                    if (pp >= P_) pp -= P_;
                    n = NS_ + cv * P_ + pp;
                }
                rr[tt] = *(const uint4v*)(vp + (((size_t)h * N_ + n) << 6) + dq);
            }
            #pragma unroll
            for (int j = 0; j < 4; ++j) {
                int d = dq + j;
                uint4v col; col.x = rr[0][j]; col.y = rr[1][j]; col.z = rr[2][j]; col.w = rr[3][j];
                uint2v hv, lv;
                split_u32x4(col, hv, lv);
                int kx = kg ^ ((d & 7) << 3);
                *(uint2v*)&VH[d][kx]  = hv;
                *(uint2v*)&VLo[d][kx] = lv;
            }
        }
        __syncthreads();

        // ---- QK^T ----
        f32x4 s[4] = {};
        #pragma unroll
        for (int ss = 0; ss < 2; ++ss) {
            #pragma unroll
            for (int nf = 0; nf < 4; ++nf) {
                int key = nf * 16 + c;
                int dx = (ss * 32 + g * 8) ^ ((key & 7) << 3);
                bf16x8 kh  = *(const bf16x8*)&KH[key][dx];
                bf16x8 klv = *(const bf16x8*)&KLo[key][dx];
                s[nf] = __builtin_amdgcn_mfma_f32_16x16x32_bf16(qh[ss], kh,  s[nf], 0, 0, 0);
                s[nf] = __builtin_amdgcn_mfma_f32_16x16x32_bf16(qh[ss], klv, s[nf], 0, 0, 0);
                s[nf] = __builtin_amdgcn_mfma_f32_16x16x32_bf16(ql[ss], kh,  s[nf], 0, 0, 0);
            }
        }

        // ---- mask + scale ----
        #pragma unroll
        for (int nf = 0; nf < 4; ++nf) {
            int col = nf * 16 + c;
            #pragma unroll
            for (int r = 0; r < 4; ++r) {
                int rowl = wr + g * 4 + r;
                bool valid;
                if (!is_pano) {
                    valid = (n0 + col) < N_;
                } else if (ch < 7) {
                    valid = (ch * 64 + col) < (NS_ + P_);
                } else {
                    int i = (ch - 7) * 64 + col;
                    valid = (i < 127) && ((unsigned)(i - rowl) < 64u);
                }
                s[nf][r] = valid ? s[nf][r] * 0.125f : -INFINITY;
            }
        }

        // ---- online softmax ----
        float fct[4];
        #pragma unroll
        for (int r = 0; r < 4; ++r) {
            float cm = fmaxf(fmaxf(s[0][r], s[1][r]), fmaxf(s[2][r], s[3][r]));
            cm = fmaxf(cm, __shfl_xor(cm, 1, 64));
            cm = fmaxf(cm, __shfl_xor(cm, 2, 64));
            cm = fmaxf(cm, __shfl_xor(cm, 4, 64));
            cm = fmaxf(cm, __shfl_xor(cm, 8, 64));
            float nm = fmaxf(m[r], cm);
            fct[r] = __expf(m[r] - nm);
            m[r] = nm;
        }

        __syncthreads();   // all waves done reading K planes

        float ps[4] = {0.f, 0.f, 0.f, 0.f};
        #pragma unroll
        for (int nf = 0; nf < 4; ++nf) {
            #pragma unroll
            for (int r = 0; r < 4; ++r) {
                float p = __expf(s[nf][r] - m[r]);
                ps[r] += p;
                HL hl2 = split2(p);
                int rowl = wr + g * 4 + r;
                int cx = (nf * 16 + c) ^ ((rowl & 7) << 3);
                KH[rowl][cx]  = hl2.h;
                KLo[rowl][cx] = hl2.l;
            }
        }
        #pragma unroll
        for (int r = 0; r < 4; ++r) {
            ps[r] += __shfl_xor(ps[r], 1, 64);
            ps[r] += __shfl_xor(ps[r], 2, 64);
            ps[r] += __shfl_xor(ps[r], 4, 64);
            ps[r] += __shfl_xor(ps[r], 8, 64);
            l[r] = l[r] * fct[r] + ps[r];
        }
        #pragma unroll
        for (int nf = 0; nf < 4; ++nf)
            #pragma unroll
            for (int r = 0; r < 4; ++r)
                o[nf][r] *= fct[r];

        // ---- P A-frags (wave-local rows, same-wave RAW) ----
        bf16x8 pah[2], pal[2];
        {
            int prow = wr + c;
            #pragma unroll
            for (int ss = 0; ss < 2; ++ss) {
                int kx = (ss * 32 + g * 8) ^ ((prow & 7) << 3);
                pah[ss] = *(const bf16x8*)&KH[prow][kx];
                pal[ss] = *(const bf16x8*)&KLo[prow][kx];
            }
        }

        // ---- PV ----
        #pragma unroll
        for (int ss = 0; ss < 2; ++ss) {
            #pragma unroll
            for (int nf = 0; nf < 4; ++nf) {
                int d = nf * 16 + c;
                int kx = (ss * 32 + g * 8) ^ ((d & 7) << 3);
                bf16x8 vh = *(const bf16x8*)&VH[d][kx];
                bf16x8 vl = *(const bf16x8*)&VLo[d][kx];
                o[nf] = __builtin_amdgcn_mfma_f32_16x16x32_bf16(pah[ss], vh, o[nf], 0, 0, 0);
                o[nf] = __builtin_amdgcn_mfma_f32_16x16x32_bf16(pah[ss], vl, o[nf], 0, 0, 0);
                o[nf] = __builtin_amdgcn_mfma_f32_16x16x32_bf16(pal[ss], vh, o[nf], 0, 0, 0);
            }
        }
        __syncthreads();
    }

    // ---- write partials ----
    unsigned int* pob = po + (size_t)slot * 4096;
    #pragma unroll
    for (int r = 0; r < 4; ++r) {
        int rowl = wr + g * 4 + r;
        #pragma unroll
        for (int nf = 0; nf < 4; ++nf) {
            HL hl2 = split2(o[nf][r]);
            pob[rowl * 64 + nf * 16 + c] = ((unsigned int)hl2.h << 16) | hl2.l;
        }
        if (c == 0) {
            pm[(size_t)slot * 64 + rowl] = m[r];
            pl[(size_t)slot * 64 + rowl] = l[r];
        }
    }
}

// ---------------------------------------------------------------------------
// Fused combine: blocks [0,336) pano (2 halves), [336,396) spatial (26 splits).
// ---------------------------------------------------------------------------
__global__ __launch_bounds__(256)
void attn_comb(const unsigned int* __restrict__ po, const float* __restrict__ pm,
               const float* __restrict__ pl,
               unsigned short* __restrict__ atthi, unsigned short* __restrict__ attlo)
{
    const int b = blockIdx.x;
    const int tid = threadIdx.x;
    if (b < 336) {
        const int pt = b % PTILES;
        const int t2 = b / PTILES;
        const int vw = t2 & 3;
        const int h  = t2 >> 2;
        const int d = tid & 63;
        const int rg = tid >> 6;
        const int tb = b * 2;

        for (int i = 0; i < 16; ++i) {
            int row = rg * 16 + i;
            int prow = pt * 64 + row;
            if (prow >= P_) break;
            float m0 = pm[(size_t)tb * 64 + row],       l0 = pl[(size_t)tb * 64 + row];
            float m1 = pm[(size_t)(tb + 1) * 64 + row], l1 = pl[(size_t)(tb + 1) * 64 + row];
            float M = fmaxf(m0, m1);
            float w0 = __expf(m0 - M), w1 = __expf(m1 - M);
            float inv = 1.0f / (l0 * w0 + l1 * w1);
            float o0 = unpk(po[(size_t)tb * 4096 + row * 64 + d]);
            float o1 = unpk(po[(size_t)(tb + 1) * 4096 + row * 64 + d]);
            float oo = (o0 * w0 + o1 * w1) * inv;
            HL hl = split2(oo);
            size_t idx = ((size_t)(NS_ + vw * P_ + prow)) * C_ + h * 64 + d;
            atthi[idx] = hl.h;
            attlo[idx] = hl.l;
        }
    } else {
        const int rid = (b - 336) * 4 + (tid >> 6);   // 0..239
        const int s = rid % NS_;
        const int h = rid / NS_;
        const int d = tid & 63;

        float M = -INFINITY;
        #pragma unroll 2
        for (int sp = 0; sp < SPL; ++sp)
            M = fmaxf(M, pm[(size_t)(NPANO + h * SPL + sp) * 64 + s]);
        float num = 0.f, den = 0.f;
        for (int sp = 0; sp < SPL; ++sp) {
            size_t sl = NPANO + h * SPL + sp;
            float w = __expf(pm[sl * 64 + s] - M);
            den = fmaf(pl[sl * 64 + s], w, den);
            num = fmaf(unpk(po[sl * 4096 + s * 64 + d]), w, num);
        }
        HL hl = split2(num / den);
        size_t idx = (size_t)s * C_ + h * 64 + d;
        atthi[idx] = hl.h;
        attlo[idx] = hl.l;
    }
}

// ---------------------------------------------------------------------------
extern "C" void kernel_launch(void* const* d_in, const int* in_sizes, int n_in,
                              void* d_out, int out_size, void* d_ws, size_t ws_size,
                              hipStream_t stream)
{
    const float* x       = (const float*)d_in[0];
    const float* qkv_w   = (const float*)d_in[1];
    const float* qkv_b   = (const float*)d_in[2];
    const float* proj_w  = (const float*)d_in[3];
    const float* proj_b  = (const float*)d_in[4];
    float* out = (float*)d_out;

    const size_t per = (size_t)H_ * N_ * D_;
    unsigned int* qp = (unsigned int*)d_ws;
    unsigned int* kp = qp + per;
    unsigned int* vp = kp + per;
    unsigned short* xhi  = (unsigned short*)(vp + per);
    unsigned short* xlo  = xhi + (size_t)N_ * C_;
    unsigned short* whi  = xlo + (size_t)N_ * C_;
    unsigned short* wlo  = whi + (size_t)3 * C_ * C_;
    unsigned short* pwhi = wlo + (size_t)3 * C_ * C_;
    unsigned short* pwlo = pwhi + (size_t)C_ * C_;
    unsigned short* atthi = pwlo + (size_t)C_ * C_;
    unsigned short* attlo = atthi + (size_t)N_ * C_;
    unsigned int* ppo = (unsigned int*)(attlo + (size_t)N_ * C_);
    float* ppm = (float*)(ppo + (size_t)NPART * 4096);
    float* ppl = ppm + (size_t)NPART * 64;

    // 0) split inputs to bf16 hi/lo
    {
        int total = N4_X + N4_W + N4_PW;
        split_all<<<(total + 255) / 256, 256, 0, stream>>>(x, qkv_w, proj_w,
                                                           xhi, xlo, whi, wlo, pwhi, pwlo);
    }

    // 1) QKV projection (MFMA, global_load_lds staging)
    gemm_mfma<1><<<13 * 36, 256, 0, stream>>>(xhi, xlo, whi, wlo, qkv_b, N_, 3 * C_,
                                              (float*)qp, (float*)kp, (float*)vp);

    // 2) unified attention partials (pano split-K + spatial split-K, all MFMA)
    attn_fused<<<NPART, 256, 0, stream>>>(qp, kp, vp, ppo, ppm, ppl);

    // 3) fused combine
    attn_comb<<<396, 256, 0, stream>>>(ppo, ppm, ppl, atthi, attlo);

    // 4) output projection (MFMA)
    gemm_mfma<0><<<13 * 12, 256, 0, stream>>>(atthi, attlo, pwhi, pwlo, proj_b, N_, C_, out, nullptr, nullptr);
}

// Round 12
// 109.935 us; speedup vs baseline: 1.0977x; 1.0977x over previous
//
#include <hip/hip_runtime.h>
#include <hip/hip_bf16.h>
#include <math.h>

#define H_  12
#define N_  1620
#define D_  64
#define C_  768
#define NS_ 20
#define V_  4
#define P_  400

#define TPP    64
#define PTILES 7    // ceil(400/64)
#define SPL    26   // spatial key splits of 64
#define NPANO  1008 // pano partial blocks: 336 tiles x 3 thirds
#define NPART  (NPANO + SPL * H_)   // 1320 total partial slots

typedef __bf16 bf16x8 __attribute__((ext_vector_type(8)));
typedef float f32x4 __attribute__((ext_vector_type(4)));
typedef unsigned short ushort8 __attribute__((ext_vector_type(8)));
typedef unsigned short ushort4v __attribute__((ext_vector_type(4)));
typedef unsigned int uint4v __attribute__((ext_vector_type(4)));

struct HL { unsigned short h, l; };

__device__ __forceinline__ unsigned short bf16_rne(float v) {
    unsigned int u = __builtin_bit_cast(unsigned int, v);
    return (unsigned short)((u + 0x7fffu + ((u >> 16) & 1u)) >> 16);
}
__device__ __forceinline__ HL split2(float v) {
    HL r;
    r.h = bf16_rne(v);
    float hf = __builtin_bit_cast(float, (unsigned int)r.h << 16);
    r.l = bf16_rne(v - hf);
    return r;
}
__device__ __forceinline__ float unpk(unsigned int u) {
    return __builtin_bit_cast(float, u & 0xffff0000u) + __builtin_bit_cast(float, u << 16);
}
__device__ __forceinline__ void unpack8(uint4v a, uint4v b, bf16x8& hi, bf16x8& lo) {
    ushort8 ea = __builtin_bit_cast(ushort8, a);
    ushort8 eb = __builtin_bit_cast(ushort8, b);
    hi = __builtin_bit_cast(bf16x8, __builtin_shufflevector(ea, eb, 1,3,5,7,9,11,13,15));
    lo = __builtin_bit_cast(bf16x8, __builtin_shufflevector(ea, eb, 0,2,4,6,8,10,12,14));
}
// bijective XCD-chunked swizzle (m204)
__device__ __forceinline__ int xcd_swz(int orig, int nwg) {
    int q = nwg >> 3, r = nwg & 7;
    int x = orig & 7, p = orig >> 3;
    return (x < r ? x * (q + 1) : r * (q + 1) + (x - r) * q) + p;
}
__device__ __forceinline__ void gload16(const void* g, void* l) {
    __builtin_amdgcn_global_load_lds((const __attribute__((address_space(1))) void*)g,
                                     (__attribute__((address_space(3))) void*)l, 16, 0, 0);
}

// ---------------------------------------------------------------------------
#define N4_X  ((N_ * C_) / 4)
#define N4_W  ((3 * C_ * C_) / 4)
#define N4_PW ((C_ * C_) / 4)

__global__ __launch_bounds__(256)
void split_all(const float* __restrict__ x, const float* __restrict__ w,
               const float* __restrict__ pw,
               unsigned short* __restrict__ xhi, unsigned short* __restrict__ xlo,
               unsigned short* __restrict__ whi, unsigned short* __restrict__ wlo,
               unsigned short* __restrict__ pwhi, unsigned short* __restrict__ pwlo)
{
    int i = blockIdx.x * 256 + threadIdx.x;
    const float* src; unsigned short* dh; unsigned short* dl; int idx;
    if (i < N4_X)                { src = x;  dh = xhi;  dl = xlo;  idx = i; }
    else if (i < N4_X + N4_W)    { src = w;  dh = whi;  dl = wlo;  idx = i - N4_X; }
    else if (i < N4_X + N4_W + N4_PW) { src = pw; dh = pwhi; dl = pwlo; idx = i - N4_X - N4_W; }
    else return;
    float4 v = ((const float4*)src)[idx];
    HL a = split2(v.x), b = split2(v.y), c = split2(v.z), d = split2(v.w);
    ushort4v h, l;
    h.x = a.h; h.y = b.h; h.z = c.h; h.w = d.h;
    l.x = a.l; l.y = b.l; l.z = c.l; l.w = d.l;
    ((ushort4v*)dh)[idx] = h;
    ((ushort4v*)dl)[idx] = l;
}

// ---------------------------------------------------------------------------
// MFMA NT GEMM, split-2 bf16. Tile 128(M) x 64(N), BK=32, 4 waves (2x2).
// Staging via global_load_lds width=16.
// ---------------------------------------------------------------------------
template<int MODE>
__global__ __launch_bounds__(256)
void gemm_mfma(const unsigned short* __restrict__ Ah, const unsigned short* __restrict__ Al,
               const unsigned short* __restrict__ Bh, const unsigned short* __restrict__ Bl,
               const float* __restrict__ bias, int M, int N,
               float* __restrict__ out0, float* __restrict__ out1, float* __restrict__ out2)
{
    __shared__ unsigned short Ash[2][128 * 32];
    __shared__ unsigned short Bsh[2][64 * 32];
    const int tid = threadIdx.x;
    const int lane = tid & 63;
    const int w = tid >> 6;

    const int wg = xcd_swz(blockIdx.x, gridDim.x);
    const int tmc = (M + 127) >> 7;
    const int tm = (wg % tmc) * 128;
    const int tn = (wg / tmc) * 64;

    const int wm = (w >> 1) * 64;
    const int wn = (w & 1) * 32;

    f32x4 acc[4][2] = {};

    const int lrow = lane >> 2;
    const int lcol = (lane & 3) * 8;

    for (int k0 = 0; k0 < 768; k0 += 32) {
        #pragma unroll
        for (int t = 0; t < 2; ++t) {
            int row = w * 32 + t * 16 + lrow;
            int gmA = tm + row; if (gmA > M - 1) gmA = M - 1;
            gload16(Ah + (size_t)gmA * 768 + k0 + lcol, &Ash[0][(w * 2 + t) * 512]);
            gload16(Al + (size_t)gmA * 768 + k0 + lcol, &Ash[1][(w * 2 + t) * 512]);
        }
        {
            int gnB = tn + w * 16 + lrow;
            gload16(Bh + (size_t)gnB * 768 + k0 + lcol, &Bsh[0][w * 512]);
            gload16(Bl + (size_t)gnB * 768 + k0 + lcol, &Bsh[1][w * 512]);
        }
        __syncthreads();

        const int fr = lane & 15;
        const int fk = (lane >> 4) * 8;
        bf16x8 ah[4], al[4], bh[2], bl[2];
        #pragma unroll
        for (int i = 0; i < 4; ++i) {
            ah[i] = *(const bf16x8*)&Ash[0][(wm + i * 16 + fr) * 32 + fk];
            al[i] = *(const bf16x8*)&Ash[1][(wm + i * 16 + fr) * 32 + fk];
        }
        #pragma unroll
        for (int i = 0; i < 2; ++i) {
            bh[i] = *(const bf16x8*)&Bsh[0][(wn + i * 16 + fr) * 32 + fk];
            bl[i] = *(const bf16x8*)&Bsh[1][(wn + i * 16 + fr) * 32 + fk];
        }
        #pragma unroll
        for (int mi = 0; mi < 4; ++mi)
            #pragma unroll
            for (int ni = 0; ni < 2; ++ni) {
                acc[mi][ni] = __builtin_amdgcn_mfma_f32_16x16x32_bf16(ah[mi], bh[ni], acc[mi][ni], 0, 0, 0);
                acc[mi][ni] = __builtin_amdgcn_mfma_f32_16x16x32_bf16(ah[mi], bl[ni], acc[mi][ni], 0, 0, 0);
                acc[mi][ni] = __builtin_amdgcn_mfma_f32_16x16x32_bf16(al[mi], bh[ni], acc[mi][ni], 0, 0, 0);
            }
        __syncthreads();
    }

    const int fr = lane & 15;
    const int fq = (lane >> 4) * 4;
    #pragma unroll
    for (int mi = 0; mi < 4; ++mi) {
        #pragma unroll
        for (int ni = 0; ni < 2; ++ni) {
            int n = tn + wn + ni * 16 + fr;
            float bb = bias[n];
            #pragma unroll
            for (int r = 0; r < 4; ++r) {
                int m = tm + wm + mi * 16 + fq + r;
                if (m >= M) continue;
                float val = acc[mi][ni][r] + bb;
                if (MODE == 0) {
                    out0[(size_t)m * N + n] = val;
                } else {
                    int which = n / C_;
                    int rr = n - which * C_;
                    int h = rr >> 6, d = rr & 63;
                    float* dst = (which == 0) ? out0 : (which == 1) ? out1 : out2;
                    HL hl2 = split2(val);
                    ((unsigned int*)dst)[((size_t)h * N_ + m) * D_ + d] =
                        ((unsigned int)hl2.h << 16) | hl2.l;
                }
            }
        }
    }
}

// ---------------------------------------------------------------------------
// Unified attention partials, MFMA flash, packed-u32 LDS (r10 format, 34.8 KB).
// Blocks [0,1008): pano, 3 chunks each (XCD swizzled; thirds of a tile
// adjacent -> same XCD). Blocks [1008,1320): spatial, 1 chunk each.
// ---------------------------------------------------------------------------
__global__ __launch_bounds__(256)
void attn_fused(const unsigned int* __restrict__ qp, const unsigned int* __restrict__ kp,
                const unsigned int* __restrict__ vp,
                unsigned int* __restrict__ po, float* __restrict__ pm, float* __restrict__ pl)
{
    __shared__ unsigned int Kl[64][68];
    __shared__ unsigned int VT[64][68];

    const int tid = threadIdx.x;
    const int lane = tid & 63;
    const int w = tid >> 6;
    const int wr = w * 16;
    const int c = lane & 15;
    const int g = lane >> 4;

    const bool is_pano = (blockIdx.x < NPANO);
    int h, vw = 0, p0 = 0, cv = 0, n0 = 0, ch_lo, ch_hi, slot;
    if (is_pano) {
        int wg = xcd_swz(blockIdx.x, NPANO);
        int third = wg % 3;
        int t = wg / 3;                 // 0..335
        int pt = t % PTILES;
        int t2 = t / PTILES;
        vw = t2 & 3;
        h  = t2 >> 2;
        p0 = pt * TPP;
        cv = (vw + 1) & 3;
        ch_lo = third * 3;
        ch_hi = third * 3 + 3;
        slot = wg;
    } else {
        int id = blockIdx.x - NPANO;
        int sp = id % SPL;
        h = id / SPL;
        n0 = sp * 64;
        ch_lo = 0; ch_hi = 1;
        slot = NPANO + id;
    }

    // ---- persistent Q A-frags ----
    bf16x8 qh[2], ql[2];
    {
        int rowq;
        if (is_pano) { rowq = NS_ + vw * P_ + p0 + wr + c; if (rowq > N_ - 1) rowq = N_ - 1; }
        else         { rowq = wr + c; if (rowq > NS_ - 1) rowq = NS_ - 1; }
        const unsigned int* qrow = qp + (((size_t)h * N_ + rowq) << 6);
        #pragma unroll
        for (int ss = 0; ss < 2; ++ss) {
            uint4v u0 = *(const uint4v*)(qrow + ss * 32 + g * 8);
            uint4v u1 = *(const uint4v*)(qrow + ss * 32 + g * 8 + 4);
            unpack8(u0, u1, qh[ss], ql[ss]);
        }
    }

    float m[4], l[4];
    f32x4 o[4] = {};
    #pragma unroll
    for (int r = 0; r < 4; ++r) { m[r] = -INFINITY; l[r] = 0.f; }

    for (int ch = ch_lo; ch < ch_hi; ++ch) {
        // ---- stage K [key][d^swz] ----
        #pragma unroll
        for (int i = 0; i < 4; ++i) {
            int f = i * 256 + tid;
            int key = f >> 4, dq = (f & 15) << 2;
            int n;
            if (!is_pano) {
                n = n0 + key; if (n > N_ - 1) n = N_ - 1;
            } else if (ch < 7) {
                int sj = ch * 64 + key;
                n = (sj < NS_) ? sj : (NS_ + vw * P_ + (sj - NS_));
                if (sj >= NS_ + P_) n = 0;
            } else {
                int pp = p0 + (ch - 7) * 64 + key;
                if (pp >= P_) pp -= P_;
                if (pp >= P_) pp -= P_;
                n = NS_ + cv * P_ + pp;
            }
            uint4v kv = *(const uint4v*)(kp + (((size_t)h * N_ + n) << 6) + dq);
            *(uint4v*)&Kl[key][dq ^ (8 * (key & 3))] = kv;
        }
        // ---- stage V transposed [d][key^swz] ----
        {
            int kg = (tid & 15) << 2;
            int dq = (tid >> 4) << 2;
            uint4v rr[4];
            #pragma unroll
            for (int tt = 0; tt < 4; ++tt) {
                int key = kg + tt;
                int n;
                if (!is_pano) {
                    n = n0 + key; if (n > N_ - 1) n = N_ - 1;
                } else if (ch < 7) {
                    int sj = ch * 64 + key;
                    n = (sj < NS_) ? sj : (NS_ + vw * P_ + (sj - NS_));
                    if (sj >= NS_ + P_) n = 0;
                } else {
                    int pp = p0 + (ch - 7) * 64 + key;
                    if (pp >= P_) pp -= P_;
                    if (pp >= P_) pp -= P_;
                    n = NS_ + cv * P_ + pp;
                }
                rr[tt] = *(const uint4v*)(vp + (((size_t)h * N_ + n) << 6) + dq);
            }
            #pragma unroll
            for (int j = 0; j < 4; ++j) {
                uint4v wv;
                wv.x = rr[0][j]; wv.y = rr[1][j]; wv.z = rr[2][j]; wv.w = rr[3][j];
                *(uint4v*)&VT[dq + j][kg ^ (8 * j)] = wv;
            }
        }
        __syncthreads();

        // ---- QK^T ----
        f32x4 s[4] = {};
        #pragma unroll
        for (int ss = 0; ss < 2; ++ss) {
            #pragma unroll
            for (int nf = 0; nf < 4; ++nf) {
                int key = nf * 16 + c;
                int db = (ss * 32 + g * 8) ^ (8 * (key & 3));
                uint4v u0 = *(const uint4v*)&Kl[key][db];
                uint4v u1 = *(const uint4v*)&Kl[key][db + 4];
                bf16x8 kh, klv;
                unpack8(u0, u1, kh, klv);
                s[nf] = __builtin_amdgcn_mfma_f32_16x16x32_bf16(qh[ss], kh,  s[nf], 0, 0, 0);
                s[nf] = __builtin_amdgcn_mfma_f32_16x16x32_bf16(qh[ss], klv, s[nf], 0, 0, 0);
                s[nf] = __builtin_amdgcn_mfma_f32_16x16x32_bf16(ql[ss], kh,  s[nf], 0, 0, 0);
            }
        }

        // ---- mask + scale ----
        #pragma unroll
        for (int nf = 0; nf < 4; ++nf) {
            int col = nf * 16 + c;
            #pragma unroll
            for (int r = 0; r < 4; ++r) {
                int rowl = wr + g * 4 + r;
                bool valid;
                if (!is_pano) {
                    valid = (n0 + col) < N_;
                } else if (ch < 7) {
                    valid = (ch * 64 + col) < (NS_ + P_);
                } else {
                    int i = (ch - 7) * 64 + col;
                    valid = (i < 127) && ((unsigned)(i - rowl) < 64u);
                }
                s[nf][r] = valid ? s[nf][r] * 0.125f : -INFINITY;
            }
        }

        // ---- online softmax ----
        float fct[4];
        #pragma unroll
        for (int r = 0; r < 4; ++r) {
            float cm = fmaxf(fmaxf(s[0][r], s[1][r]), fmaxf(s[2][r], s[3][r]));
            cm = fmaxf(cm, __shfl_xor(cm, 1, 64));
            cm = fmaxf(cm, __shfl_xor(cm, 2, 64));
            cm = fmaxf(cm, __shfl_xor(cm, 4, 64));
            cm = fmaxf(cm, __shfl_xor(cm, 8, 64));
            float nm = fmaxf(m[r], cm);
            fct[r] = __expf(m[r] - nm);
            m[r] = nm;
        }

        __syncthreads();   // all waves done reading Kl as K

        float ps[4] = {0.f, 0.f, 0.f, 0.f};
        #pragma unroll
        for (int nf = 0; nf < 4; ++nf) {
            #pragma unroll
            for (int r = 0; r < 4; ++r) {
                float p = __expf(s[nf][r] - m[r]);
                ps[r] += p;
                HL hl2 = split2(p);
                int rowl = wr + g * 4 + r;
                int col = (nf * 16 + c) ^ (8 * (rowl & 3));
                Kl[rowl][col] = ((unsigned int)hl2.h << 16) | hl2.l;
            }
        }
        #pragma unroll
        for (int r = 0; r < 4; ++r) {
            ps[r] += __shfl_xor(ps[r], 1, 64);
            ps[r] += __shfl_xor(ps[r], 2, 64);
            ps[r] += __shfl_xor(ps[r], 4, 64);
            ps[r] += __shfl_xor(ps[r], 8, 64);
            l[r] = l[r] * fct[r] + ps[r];
        }
        #pragma unroll
        for (int nf = 0; nf < 4; ++nf)
            #pragma unroll
            for (int r = 0; r < 4; ++r)
                o[nf][r] *= fct[r];

        // ---- P A-frags (wave-local rows, same-wave RAW) ----
        bf16x8 pah[2], pal[2];
        {
            int prow = wr + c;
            int xw = 8 * (prow & 3);
            #pragma unroll
            for (int ss = 0; ss < 2; ++ss) {
                int kb = (ss * 32 + g * 8) ^ xw;
                uint4v u0 = *(const uint4v*)&Kl[prow][kb];
                uint4v u1 = *(const uint4v*)&Kl[prow][kb + 4];
                unpack8(u0, u1, pah[ss], pal[ss]);
            }
        }

        // ---- PV ----
        int xv = 8 * (c & 3);
        #pragma unroll
        for (int ss = 0; ss < 2; ++ss) {
            #pragma unroll
            for (int nf = 0; nf < 4; ++nf) {
                int d = nf * 16 + c;
                int kb = (ss * 32 + g * 8) ^ xv;
                uint4v u0 = *(const uint4v*)&VT[d][kb];
                uint4v u1 = *(const uint4v*)&VT[d][kb + 4];
                bf16x8 vh, vl;
                unpack8(u0, u1, vh, vl);
                o[nf] = __builtin_amdgcn_mfma_f32_16x16x32_bf16(pah[ss], vh, o[nf], 0, 0, 0);
                o[nf] = __builtin_amdgcn_mfma_f32_16x16x32_bf16(pah[ss], vl, o[nf], 0, 0, 0);
                o[nf] = __builtin_amdgcn_mfma_f32_16x16x32_bf16(pal[ss], vh, o[nf], 0, 0, 0);
            }
        }
        __syncthreads();
    }

    // ---- write partials ----
    unsigned int* pob = po + (size_t)slot * 4096;
    #pragma unroll
    for (int r = 0; r < 4; ++r) {
        int rowl = wr + g * 4 + r;
        #pragma unroll
        for (int nf = 0; nf < 4; ++nf) {
            HL hl2 = split2(o[nf][r]);
            pob[rowl * 64 + nf * 16 + c] = ((unsigned int)hl2.h << 16) | hl2.l;
        }
        if (c == 0) {
            pm[(size_t)slot * 64 + rowl] = m[r];
            pl[(size_t)slot * 64 + rowl] = l[r];
        }
    }
}

// ---------------------------------------------------------------------------
// Fused combine: blocks [0,336) pano (3 thirds), [336,396) spatial (26 splits).
// ---------------------------------------------------------------------------
__global__ __launch_bounds__(256)
void attn_comb(const unsigned int* __restrict__ po, const float* __restrict__ pm,
               const float* __restrict__ pl,
               unsigned short* __restrict__ atthi, unsigned short* __restrict__ attlo)
{
    const int b = blockIdx.x;
    const int tid = threadIdx.x;
    if (b < 336) {
        const int pt = b % PTILES;
        const int t2 = b / PTILES;
        const int vw = t2 & 3;
        const int h  = t2 >> 2;
        const int d = tid & 63;
        const int rg = tid >> 6;
        const int tb = b * 3;

        for (int i = 0; i < 16; ++i) {
            int row = rg * 16 + i;
            int prow = pt * 64 + row;
            if (prow >= P_) break;
            float m0 = pm[(size_t)tb * 64 + row],       l0 = pl[(size_t)tb * 64 + row];
            float m1 = pm[(size_t)(tb + 1) * 64 + row], l1 = pl[(size_t)(tb + 1) * 64 + row];
            float m2 = pm[(size_t)(tb + 2) * 64 + row], l2 = pl[(size_t)(tb + 2) * 64 + row];
            float M = fmaxf(fmaxf(m0, m1), m2);
            float w0 = __expf(m0 - M), w1 = __expf(m1 - M), w2 = __expf(m2 - M);
            float inv = 1.0f / (l0 * w0 + l1 * w1 + l2 * w2);
            float o0 = unpk(po[(size_t)tb * 4096 + row * 64 + d]);
            float o1 = unpk(po[(size_t)(tb + 1) * 4096 + row * 64 + d]);
            float o2 = unpk(po[(size_t)(tb + 2) * 4096 + row * 64 + d]);
            float oo = (o0 * w0 + o1 * w1 + o2 * w2) * inv;
            HL hl = split2(oo);
            size_t idx = ((size_t)(NS_ + vw * P_ + prow)) * C_ + h * 64 + d;
            atthi[idx] = hl.h;
            attlo[idx] = hl.l;
        }
    } else {
        const int rid = (b - 336) * 4 + (tid >> 6);   // 0..239
        const int s = rid % NS_;
        const int h = rid / NS_;
        const int d = tid & 63;

        float M = -INFINITY;
        #pragma unroll 2
        for (int sp = 0; sp < SPL; ++sp)
            M = fmaxf(M, pm[(size_t)(NPANO + h * SPL + sp) * 64 + s]);
        float num = 0.f, den = 0.f;
        for (int sp = 0; sp < SPL; ++sp) {
            size_t sl = NPANO + h * SPL + sp;
            float w = __expf(pm[sl * 64 + s] - M);
            den = fmaf(pl[sl * 64 + s], w, den);
            num = fmaf(unpk(po[sl * 4096 + s * 64 + d]), w, num);
        }
        HL hl = split2(num / den);
        size_t idx = (size_t)s * C_ + h * 64 + d;
        atthi[idx] = hl.h;
        attlo[idx] = hl.l;
    }
}

// ---------------------------------------------------------------------------
extern "C" void kernel_launch(void* const* d_in, const int* in_sizes, int n_in,
                              void* d_out, int out_size, void* d_ws, size_t ws_size,
                              hipStream_t stream)
{
    const float* x       = (const float*)d_in[0];
    const float* qkv_w   = (const float*)d_in[1];
    const float* qkv_b   = (const float*)d_in[2];
    const float* proj_w  = (const float*)d_in[3];
    const float* proj_b  = (const float*)d_in[4];
    float* out = (float*)d_out;

    const size_t per = (size_t)H_ * N_ * D_;
    unsigned int* qp = (unsigned int*)d_ws;
    unsigned int* kp = qp + per;
    unsigned int* vp = kp + per;
    unsigned short* xhi  = (unsigned short*)(vp + per);
    unsigned short* xlo  = xhi + (size_t)N_ * C_;
    unsigned short* whi  = xlo + (size_t)N_ * C_;
    unsigned short* wlo  = whi + (size_t)3 * C_ * C_;
    unsigned short* pwhi = wlo + (size_t)3 * C_ * C_;
    unsigned short* pwlo = pwhi + (size_t)C_ * C_;
    unsigned short* atthi = pwlo + (size_t)C_ * C_;
    unsigned short* attlo = atthi + (size_t)N_ * C_;
    unsigned int* ppo = (unsigned int*)(attlo + (size_t)N_ * C_);
    float* ppm = (float*)(ppo + (size_t)NPART * 4096);
    float* ppl = ppm + (size_t)NPART * 64;

    // 0) split inputs to bf16 hi/lo
    {
        int total = N4_X + N4_W + N4_PW;
        split_all<<<(total + 255) / 256, 256, 0, stream>>>(x, qkv_w, proj_w,
                                                           xhi, xlo, whi, wlo, pwhi, pwlo);
    }

    // 1) QKV projection (MFMA, global_load_lds staging)
    gemm_mfma<1><<<13 * 36, 256, 0, stream>>>(xhi, xlo, whi, wlo, qkv_b, N_, 3 * C_,
                                              (float*)qp, (float*)kp, (float*)vp);

    // 2) unified attention partials (pano 3-way split-K + spatial split-K)
    attn_fused<<<NPART, 256, 0, stream>>>(qp, kp, vp, ppo, ppm, ppl);

    // 3) fused combine
    attn_comb<<<396, 256, 0, stream>>>(ppo, ppm, ppl, atthi, attlo);

    // 4) output projection (MFMA)
    gemm_mfma<0><<<13 * 12, 256, 0, stream>>>(atthi, attlo, pwhi, pwlo, proj_b, N_, C_, out, nullptr, nullptr);
}

// Round 13
// 109.087 us; speedup vs baseline: 1.1062x; 1.0078x over previous
//
#include <hip/hip_runtime.h>
#include <hip/hip_bf16.h>
#include <math.h>

#define H_  12
#define N_  1620
#define D_  64
#define C_  768
#define NS_ 20
#define V_  4
#define P_  400

#define TPP    64
#define PTILES 7    // ceil(400/64)
#define SPL    26   // spatial key splits of 64
#define NPANO  1008 // pano partial blocks: 336 tiles x 3 thirds
#define NPART  (NPANO + SPL * H_)   // 1320 total partial slots

typedef __bf16 bf16x8 __attribute__((ext_vector_type(8)));
typedef float f32x4 __attribute__((ext_vector_type(4)));
typedef unsigned short ushort8 __attribute__((ext_vector_type(8)));
typedef unsigned short ushort4v __attribute__((ext_vector_type(4)));
typedef unsigned int uint4v __attribute__((ext_vector_type(4)));

struct HL { unsigned short h, l; };

__device__ __forceinline__ unsigned short bf16_rne(float v) {
    unsigned int u = __builtin_bit_cast(unsigned int, v);
    return (unsigned short)((u + 0x7fffu + ((u >> 16) & 1u)) >> 16);
}
__device__ __forceinline__ HL split2(float v) {
    HL r;
    r.h = bf16_rne(v);
    float hf = __builtin_bit_cast(float, (unsigned int)r.h << 16);
    r.l = bf16_rne(v - hf);
    return r;
}
__device__ __forceinline__ float unpk(unsigned int u) {
    return __builtin_bit_cast(float, u & 0xffff0000u) + __builtin_bit_cast(float, u << 16);
}
__device__ __forceinline__ void unpack8(uint4v a, uint4v b, bf16x8& hi, bf16x8& lo) {
    ushort8 ea = __builtin_bit_cast(ushort8, a);
    ushort8 eb = __builtin_bit_cast(ushort8, b);
    hi = __builtin_bit_cast(bf16x8, __builtin_shufflevector(ea, eb, 1,3,5,7,9,11,13,15));
    lo = __builtin_bit_cast(bf16x8, __builtin_shufflevector(ea, eb, 0,2,4,6,8,10,12,14));
}
// bijective XCD-chunked swizzle (m204)
__device__ __forceinline__ int xcd_swz(int orig, int nwg) {
    int q = nwg >> 3, r = nwg & 7;
    int x = orig & 7, p = orig >> 3;
    return (x < r ? x * (q + 1) : r * (q + 1) + (x - r) * q) + p;
}
__device__ __forceinline__ void gload16(const void* g, void* l) {
    __builtin_amdgcn_global_load_lds((const __attribute__((address_space(1))) void*)g,
                                     (__attribute__((address_space(3))) void*)l, 16, 0, 0);
}

// ---------------------------------------------------------------------------
#define N4_X  ((N_ * C_) / 4)
#define N4_W  ((3 * C_ * C_) / 4)
#define N4_PW ((C_ * C_) / 4)

__global__ __launch_bounds__(256)
void split_all(const float* __restrict__ x, const float* __restrict__ w,
               const float* __restrict__ pw,
               unsigned short* __restrict__ xhi, unsigned short* __restrict__ xlo,
               unsigned short* __restrict__ whi, unsigned short* __restrict__ wlo,
               unsigned short* __restrict__ pwhi, unsigned short* __restrict__ pwlo)
{
    int i = blockIdx.x * 256 + threadIdx.x;
    const float* src; unsigned short* dh; unsigned short* dl; int idx;
    if (i < N4_X)                { src = x;  dh = xhi;  dl = xlo;  idx = i; }
    else if (i < N4_X + N4_W)    { src = w;  dh = whi;  dl = wlo;  idx = i - N4_X; }
    else if (i < N4_X + N4_W + N4_PW) { src = pw; dh = pwhi; dl = pwlo; idx = i - N4_X - N4_W; }
    else return;
    float4 v = ((const float4*)src)[idx];
    HL a = split2(v.x), b = split2(v.y), c = split2(v.z), d = split2(v.w);
    ushort4v h, l;
    h.x = a.h; h.y = b.h; h.z = c.h; h.w = d.h;
    l.x = a.l; l.y = b.l; l.z = c.l; l.w = d.l;
    ((ushort4v*)dh)[idx] = h;
    ((ushort4v*)dl)[idx] = l;
}

// ---------------------------------------------------------------------------
// MFMA NT GEMM, split-2 bf16. Tile 64(M) x 64(N), BK=32, 4 waves (2x2, each
// 32x32). Double-buffered LDS (2-phase T3 recipe): STAGE(next) issued before
// compute(cur); single __syncthreads per k-step (its vmcnt(0) drain lands
// the prefetch). Staging via global_load_lds width=16, layout linear in tid.
// ---------------------------------------------------------------------------
template<int MODE>
__global__ __launch_bounds__(256)
void gemm_mfma(const unsigned short* __restrict__ Ah, const unsigned short* __restrict__ Al,
               const unsigned short* __restrict__ Bh, const unsigned short* __restrict__ Bl,
               const float* __restrict__ bias, int M, int N,
               float* __restrict__ out0, float* __restrict__ out1, float* __restrict__ out2)
{
    __shared__ unsigned short Ash[2][2][64 * 32];   // [buf][hi/lo]
    __shared__ unsigned short Bsh[2][2][64 * 32];
    const int tid = threadIdx.x;
    const int lane = tid & 63;
    const int w = tid >> 6;

    const int wg = xcd_swz(blockIdx.x, gridDim.x);
    const int tmc = (M + 63) >> 6;
    const int tm = (wg % tmc) * 64;
    const int tn = (wg / tmc) * 64;

    const int wm = (w >> 1) * 32;
    const int wn = (w & 1) * 32;

    f32x4 acc[2][2] = {};

    // staging address: wave w covers rows w*16..w*16+15 of the 64-row panel
    const int lrow = lane >> 2;
    const int lcol = (lane & 3) * 8;
    int gmA = tm + w * 16 + lrow; if (gmA > M - 1) gmA = M - 1;
    const int gnB = tn + w * 16 + lrow;
    const size_t aoff = (size_t)gmA * 768 + lcol;
    const size_t boff = (size_t)gnB * 768 + lcol;

    auto STAGE = [&](int buf, int k0) {
        gload16(Ah + aoff + k0, &Ash[buf][0][w * 512]);
        gload16(Al + aoff + k0, &Ash[buf][1][w * 512]);
        gload16(Bh + boff + k0, &Bsh[buf][0][w * 512]);
        gload16(Bl + boff + k0, &Bsh[buf][1][w * 512]);
    };
    auto COMPUTE = [&](int buf) {
        const int fr = lane & 15;
        const int fk = (lane >> 4) * 8;
        bf16x8 ah[2], al[2], bh[2], bl[2];
        #pragma unroll
        for (int i = 0; i < 2; ++i) {
            ah[i] = *(const bf16x8*)&Ash[buf][0][(wm + i * 16 + fr) * 32 + fk];
            al[i] = *(const bf16x8*)&Ash[buf][1][(wm + i * 16 + fr) * 32 + fk];
            bh[i] = *(const bf16x8*)&Bsh[buf][0][(wn + i * 16 + fr) * 32 + fk];
            bl[i] = *(const bf16x8*)&Bsh[buf][1][(wn + i * 16 + fr) * 32 + fk];
        }
        #pragma unroll
        for (int mi = 0; mi < 2; ++mi)
            #pragma unroll
            for (int ni = 0; ni < 2; ++ni) {
                acc[mi][ni] = __builtin_amdgcn_mfma_f32_16x16x32_bf16(ah[mi], bh[ni], acc[mi][ni], 0, 0, 0);
                acc[mi][ni] = __builtin_amdgcn_mfma_f32_16x16x32_bf16(ah[mi], bl[ni], acc[mi][ni], 0, 0, 0);
                acc[mi][ni] = __builtin_amdgcn_mfma_f32_16x16x32_bf16(al[mi], bh[ni], acc[mi][ni], 0, 0, 0);
            }
    };

    // prologue
    STAGE(0, 0);
    __syncthreads();
    int cur = 0;
    for (int t = 0; t < 23; ++t) {
        STAGE(cur ^ 1, (t + 1) * 32);   // prefetch next k-step
        COMPUTE(cur);                   // compute current
        __syncthreads();                // drains vmcnt -> next buffer ready
        cur ^= 1;
    }
    COMPUTE(cur);                       // epilogue step (no prefetch)

    const int fr = lane & 15;
    const int fq = (lane >> 4) * 4;
    #pragma unroll
    for (int mi = 0; mi < 2; ++mi) {
        #pragma unroll
        for (int ni = 0; ni < 2; ++ni) {
            int n = tn + wn + ni * 16 + fr;
            float bb = bias[n];
            #pragma unroll
            for (int r = 0; r < 4; ++r) {
                int m = tm + wm + mi * 16 + fq + r;
                if (m >= M) continue;
                float val = acc[mi][ni][r] + bb;
                if (MODE == 0) {
                    out0[(size_t)m * N + n] = val;
                } else {
                    int which = n / C_;
                    int rr = n - which * C_;
                    int h = rr >> 6, d = rr & 63;
                    float* dst = (which == 0) ? out0 : (which == 1) ? out1 : out2;
                    HL hl2 = split2(val);
                    ((unsigned int*)dst)[((size_t)h * N_ + m) * D_ + d] =
                        ((unsigned int)hl2.h << 16) | hl2.l;
                }
            }
        }
    }
}

// ---------------------------------------------------------------------------
// Unified attention partials, MFMA flash, packed-u32 LDS (34.8 KB).
// Blocks [0,1008): pano, 3 chunks each (XCD swizzled). [1008,1320): spatial.
// ---------------------------------------------------------------------------
__global__ __launch_bounds__(256)
void attn_fused(const unsigned int* __restrict__ qp, const unsigned int* __restrict__ kp,
                const unsigned int* __restrict__ vp,
                unsigned int* __restrict__ po, float* __restrict__ pm, float* __restrict__ pl)
{
    __shared__ unsigned int Kl[64][68];
    __shared__ unsigned int VT[64][68];

    const int tid = threadIdx.x;
    const int lane = tid & 63;
    const int w = tid >> 6;
    const int wr = w * 16;
    const int c = lane & 15;
    const int g = lane >> 4;

    const bool is_pano = (blockIdx.x < NPANO);
    int h, vw = 0, p0 = 0, cv = 0, n0 = 0, ch_lo, ch_hi, slot;
    if (is_pano) {
        int wg = xcd_swz(blockIdx.x, NPANO);
        int third = wg % 3;
        int t = wg / 3;
        int pt = t % PTILES;
        int t2 = t / PTILES;
        vw = t2 & 3;
        h  = t2 >> 2;
        p0 = pt * TPP;
        cv = (vw + 1) & 3;
        ch_lo = third * 3;
        ch_hi = third * 3 + 3;
        slot = wg;
    } else {
        int id = blockIdx.x - NPANO;
        int sp = id % SPL;
        h = id / SPL;
        n0 = sp * 64;
        ch_lo = 0; ch_hi = 1;
        slot = NPANO + id;
    }

    bf16x8 qh[2], ql[2];
    {
        int rowq;
        if (is_pano) { rowq = NS_ + vw * P_ + p0 + wr + c; if (rowq > N_ - 1) rowq = N_ - 1; }
        else         { rowq = wr + c; if (rowq > NS_ - 1) rowq = NS_ - 1; }
        const unsigned int* qrow = qp + (((size_t)h * N_ + rowq) << 6);
        #pragma unroll
        for (int ss = 0; ss < 2; ++ss) {
            uint4v u0 = *(const uint4v*)(qrow + ss * 32 + g * 8);
            uint4v u1 = *(const uint4v*)(qrow + ss * 32 + g * 8 + 4);
            unpack8(u0, u1, qh[ss], ql[ss]);
        }
    }

    float m[4], l[4];
    f32x4 o[4] = {};
    #pragma unroll
    for (int r = 0; r < 4; ++r) { m[r] = -INFINITY; l[r] = 0.f; }

    for (int ch = ch_lo; ch < ch_hi; ++ch) {
        #pragma unroll
        for (int i = 0; i < 4; ++i) {
            int f = i * 256 + tid;
            int key = f >> 4, dq = (f & 15) << 2;
            int n;
            if (!is_pano) {
                n = n0 + key; if (n > N_ - 1) n = N_ - 1;
            } else if (ch < 7) {
                int sj = ch * 64 + key;
                n = (sj < NS_) ? sj : (NS_ + vw * P_ + (sj - NS_));
                if (sj >= NS_ + P_) n = 0;
            } else {
                int pp = p0 + (ch - 7) * 64 + key;
                if (pp >= P_) pp -= P_;
                if (pp >= P_) pp -= P_;
                n = NS_ + cv * P_ + pp;
            }
            uint4v kv = *(const uint4v*)(kp + (((size_t)h * N_ + n) << 6) + dq);
            *(uint4v*)&Kl[key][dq ^ (8 * (key & 3))] = kv;
        }
        {
            int kg = (tid & 15) << 2;
            int dq = (tid >> 4) << 2;
            uint4v rr[4];
            #pragma unroll
            for (int tt = 0; tt < 4; ++tt) {
                int key = kg + tt;
                int n;
                if (!is_pano) {
                    n = n0 + key; if (n > N_ - 1) n = N_ - 1;
                } else if (ch < 7) {
                    int sj = ch * 64 + key;
                    n = (sj < NS_) ? sj : (NS_ + vw * P_ + (sj - NS_));
                    if (sj >= NS_ + P_) n = 0;
                } else {
                    int pp = p0 + (ch - 7) * 64 + key;
                    if (pp >= P_) pp -= P_;
                    if (pp >= P_) pp -= P_;
                    n = NS_ + cv * P_ + pp;
                }
                rr[tt] = *(const uint4v*)(vp + (((size_t)h * N_ + n) << 6) + dq);
            }
            #pragma unroll
            for (int j = 0; j < 4; ++j) {
                uint4v wv;
                wv.x = rr[0][j]; wv.y = rr[1][j]; wv.z = rr[2][j]; wv.w = rr[3][j];
                *(uint4v*)&VT[dq + j][kg ^ (8 * j)] = wv;
            }
        }
        __syncthreads();

        f32x4 s[4] = {};
        #pragma unroll
        for (int ss = 0; ss < 2; ++ss) {
            #pragma unroll
            for (int nf = 0; nf < 4; ++nf) {
                int key = nf * 16 + c;
                int db = (ss * 32 + g * 8) ^ (8 * (key & 3));
                uint4v u0 = *(const uint4v*)&Kl[key][db];
                uint4v u1 = *(const uint4v*)&Kl[key][db + 4];
                bf16x8 kh, klv;
                unpack8(u0, u1, kh, klv);
                s[nf] = __builtin_amdgcn_mfma_f32_16x16x32_bf16(qh[ss], kh,  s[nf], 0, 0, 0);
                s[nf] = __builtin_amdgcn_mfma_f32_16x16x32_bf16(qh[ss], klv, s[nf], 0, 0, 0);
                s[nf] = __builtin_amdgcn_mfma_f32_16x16x32_bf16(ql[ss], kh,  s[nf], 0, 0, 0);
            }
        }

        #pragma unroll
        for (int nf = 0; nf < 4; ++nf) {
            int col = nf * 16 + c;
            #pragma unroll
            for (int r = 0; r < 4; ++r) {
                int rowl = wr + g * 4 + r;
                bool valid;
                if (!is_pano) {
                    valid = (n0 + col) < N_;
                } else if (ch < 7) {
                    valid = (ch * 64 + col) < (NS_ + P_);
                } else {
                    int i = (ch - 7) * 64 + col;
                    valid = (i < 127) && ((unsigned)(i - rowl) < 64u);
                }
                s[nf][r] = valid ? s[nf][r] * 0.125f : -INFINITY;
            }
        }

        float fct[4];
        #pragma unroll
        for (int r = 0; r < 4; ++r) {
            float cm = fmaxf(fmaxf(s[0][r], s[1][r]), fmaxf(s[2][r], s[3][r]));
            cm = fmaxf(cm, __shfl_xor(cm, 1, 64));
            cm = fmaxf(cm, __shfl_xor(cm, 2, 64));
            cm = fmaxf(cm, __shfl_xor(cm, 4, 64));
            cm = fmaxf(cm, __shfl_xor(cm, 8, 64));
            float nm = fmaxf(m[r], cm);
            fct[r] = __expf(m[r] - nm);
            m[r] = nm;
        }

        __syncthreads();

        float ps[4] = {0.f, 0.f, 0.f, 0.f};
        #pragma unroll
        for (int nf = 0; nf < 4; ++nf) {
            #pragma unroll
            for (int r = 0; r < 4; ++r) {
                float p = __expf(s[nf][r] - m[r]);
                ps[r] += p;
                HL hl2 = split2(p);
                int rowl = wr + g * 4 + r;
                int col = (nf * 16 + c) ^ (8 * (rowl & 3));
                Kl[rowl][col] = ((unsigned int)hl2.h << 16) | hl2.l;
            }
        }
        #pragma unroll
        for (int r = 0; r < 4; ++r) {
            ps[r] += __shfl_xor(ps[r], 1, 64);
            ps[r] += __shfl_xor(ps[r], 2, 64);
            ps[r] += __shfl_xor(ps[r], 4, 64);
            ps[r] += __shfl_xor(ps[r], 8, 64);
            l[r] = l[r] * fct[r] + ps[r];
        }
        #pragma unroll
        for (int nf = 0; nf < 4; ++nf)
            #pragma unroll
            for (int r = 0; r < 4; ++r)
                o[nf][r] *= fct[r];

        bf16x8 pah[2], pal[2];
        {
            int prow = wr + c;
            int xw = 8 * (prow & 3);
            #pragma unroll
            for (int ss = 0; ss < 2; ++ss) {
                int kb = (ss * 32 + g * 8) ^ xw;
                uint4v u0 = *(const uint4v*)&Kl[prow][kb];
                uint4v u1 = *(const uint4v*)&Kl[prow][kb + 4];
                unpack8(u0, u1, pah[ss], pal[ss]);
            }
        }

        int xv = 8 * (c & 3);
        #pragma unroll
        for (int ss = 0; ss < 2; ++ss) {
            #pragma unroll
            for (int nf = 0; nf < 4; ++nf) {
                int d = nf * 16 + c;
                int kb = (ss * 32 + g * 8) ^ xv;
                uint4v u0 = *(const uint4v*)&VT[d][kb];
                uint4v u1 = *(const uint4v*)&VT[d][kb + 4];
                bf16x8 vh, vl;
                unpack8(u0, u1, vh, vl);
                o[nf] = __builtin_amdgcn_mfma_f32_16x16x32_bf16(pah[ss], vh, o[nf], 0, 0, 0);
                o[nf] = __builtin_amdgcn_mfma_f32_16x16x32_bf16(pah[ss], vl, o[nf], 0, 0, 0);
                o[nf] = __builtin_amdgcn_mfma_f32_16x16x32_bf16(pal[ss], vh, o[nf], 0, 0, 0);
            }
        }
        __syncthreads();
    }

    unsigned int* pob = po + (size_t)slot * 4096;
    #pragma unroll
    for (int r = 0; r < 4; ++r) {
        int rowl = wr + g * 4 + r;
        #pragma unroll
        for (int nf = 0; nf < 4; ++nf) {
            HL hl2 = split2(o[nf][r]);
            pob[rowl * 64 + nf * 16 + c] = ((unsigned int)hl2.h << 16) | hl2.l;
        }
        if (c == 0) {
            pm[(size_t)slot * 64 + rowl] = m[r];
            pl[(size_t)slot * 64 + rowl] = l[r];
        }
    }
}

// ---------------------------------------------------------------------------
// Fused combine: blocks [0,336) pano (3 thirds), [336,396) spatial (26 splits).
// ---------------------------------------------------------------------------
__global__ __launch_bounds__(256)
void attn_comb(const unsigned int* __restrict__ po, const float* __restrict__ pm,
               const float* __restrict__ pl,
               unsigned short* __restrict__ atthi, unsigned short* __restrict__ attlo)
{
    const int b = blockIdx.x;
    const int tid = threadIdx.x;
    if (b < 336) {
        const int pt = b % PTILES;
        const int t2 = b / PTILES;
        const int vw = t2 & 3;
        const int h  = t2 >> 2;
        const int d = tid & 63;
        const int rg = tid >> 6;
        const int tb = b * 3;

        for (int i = 0; i < 16; ++i) {
            int row = rg * 16 + i;
            int prow = pt * 64 + row;
            if (prow >= P_) break;
            float m0 = pm[(size_t)tb * 64 + row],       l0 = pl[(size_t)tb * 64 + row];
            float m1 = pm[(size_t)(tb + 1) * 64 + row], l1 = pl[(size_t)(tb + 1) * 64 + row];
            float m2 = pm[(size_t)(tb + 2) * 64 + row], l2 = pl[(size_t)(tb + 2) * 64 + row];
            float M = fmaxf(fmaxf(m0, m1), m2);
            float w0 = __expf(m0 - M), w1 = __expf(m1 - M), w2 = __expf(m2 - M);
            float inv = 1.0f / (l0 * w0 + l1 * w1 + l2 * w2);
            float o0 = unpk(po[(size_t)tb * 4096 + row * 64 + d]);
            float o1 = unpk(po[(size_t)(tb + 1) * 4096 + row * 64 + d]);
            float o2 = unpk(po[(size_t)(tb + 2) * 4096 + row * 64 + d]);
            float oo = (o0 * w0 + o1 * w1 + o2 * w2) * inv;
            HL hl = split2(oo);
            size_t idx = ((size_t)(NS_ + vw * P_ + prow)) * C_ + h * 64 + d;
            atthi[idx] = hl.h;
            attlo[idx] = hl.l;
        }
    } else {
        const int rid = (b - 336) * 4 + (tid >> 6);   // 0..239
        const int s = rid % NS_;
        const int h = rid / NS_;
        const int d = tid & 63;

        float M = -INFINITY;
        #pragma unroll 2
        for (int sp = 0; sp < SPL; ++sp)
            M = fmaxf(M, pm[(size_t)(NPANO + h * SPL + sp) * 64 + s]);
        float num = 0.f, den = 0.f;
        for (int sp = 0; sp < SPL; ++sp) {
            size_t sl = NPANO + h * SPL + sp;
            float w = __expf(pm[sl * 64 + s] - M);
            den = fmaf(pl[sl * 64 + s], w, den);
            num = fmaf(unpk(po[sl * 4096 + s * 64 + d]), w, num);
        }
        HL hl = split2(num / den);
        size_t idx = (size_t)s * C_ + h * 64 + d;
        atthi[idx] = hl.h;
        attlo[idx] = hl.l;
    }
}

// ---------------------------------------------------------------------------
extern "C" void kernel_launch(void* const* d_in, const int* in_sizes, int n_in,
                              void* d_out, int out_size, void* d_ws, size_t ws_size,
                              hipStream_t stream)
{
    const float* x       = (const float*)d_in[0];
    const float* qkv_w   = (const float*)d_in[1];
    const float* qkv_b   = (const float*)d_in[2];
    const float* proj_w  = (const float*)d_in[3];
    const float* proj_b  = (const float*)d_in[4];
    float* out = (float*)d_out;

    const size_t per = (size_t)H_ * N_ * D_;
    unsigned int* qp = (unsigned int*)d_ws;
    unsigned int* kp = qp + per;
    unsigned int* vp = kp + per;
    unsigned short* xhi  = (unsigned short*)(vp + per);
    unsigned short* xlo  = xhi + (size_t)N_ * C_;
    unsigned short* whi  = xlo + (size_t)N_ * C_;
    unsigned short* wlo  = whi + (size_t)3 * C_ * C_;
    unsigned short* pwhi = wlo + (size_t)3 * C_ * C_;
    unsigned short* pwlo = pwhi + (size_t)C_ * C_;
    unsigned short* atthi = pwlo + (size_t)C_ * C_;
    unsigned short* attlo = atthi + (size_t)N_ * C_;
    unsigned int* ppo = (unsigned int*)(attlo + (size_t)N_ * C_);
    float* ppm = (float*)(ppo + (size_t)NPART * 4096);
    float* ppl = ppm + (size_t)NPART * 64;

    // 0) split inputs to bf16 hi/lo
    {
        int total = N4_X + N4_W + N4_PW;
        split_all<<<(total + 255) / 256, 256, 0, stream>>>(x, qkv_w, proj_w,
                                                           xhi, xlo, whi, wlo, pwhi, pwlo);
    }

    // 1) QKV projection (MFMA, 64x64 double-buffered)
    gemm_mfma<1><<<26 * 36, 256, 0, stream>>>(xhi, xlo, whi, wlo, qkv_b, N_, 3 * C_,
                                              (float*)qp, (float*)kp, (float*)vp);

    // 2) unified attention partials (pano 3-way split-K + spatial split-K)
    attn_fused<<<NPART, 256, 0, stream>>>(qp, kp, vp, ppo, ppm, ppl);

    // 3) fused combine
    attn_comb<<<396, 256, 0, stream>>>(ppo, ppm, ppl, atthi, attlo);

    // 4) output projection (MFMA, 64x64 double-buffered)
    gemm_mfma<0><<<26 * 12, 256, 0, stream>>>(atthi, attlo, pwhi, pwlo, proj_b, N_, C_, out, nullptr, nullptr);
}

// Round 14
// 97.614 us; speedup vs baseline: 1.2362x; 1.1175x over previous
//
#include <hip/hip_runtime.h>
#include <hip/hip_bf16.h>
#include <math.h>

#define H_  12
#define N_  1620
#define D_  64
#define C_  768
#define NS_ 20
#define V_  4
#define P_  400

#define TPP    64
#define PTILES 7    // ceil(400/64)
#define SPL    26   // spatial key splits of 64
#define NPANO  1008 // pano partial blocks: 336 tiles x 3 thirds
#define NPART  (NPANO + SPL * H_)   // 1320 total partial slots

typedef __bf16 bf16x8 __attribute__((ext_vector_type(8)));
typedef _Float16 f16x8 __attribute__((ext_vector_type(8)));
typedef float f32x4 __attribute__((ext_vector_type(4)));
typedef unsigned short ushort8 __attribute__((ext_vector_type(8)));
typedef unsigned short ushort4v __attribute__((ext_vector_type(4)));
typedef unsigned int uint4v __attribute__((ext_vector_type(4)));

struct HL { unsigned short h, l; };

__device__ __forceinline__ unsigned short bf16_rne(float v) {
    unsigned int u = __builtin_bit_cast(unsigned int, v);
    return (unsigned short)((u + 0x7fffu + ((u >> 16) & 1u)) >> 16);
}
__device__ __forceinline__ HL split2(float v) {
    HL r;
    r.h = bf16_rne(v);
    float hf = __builtin_bit_cast(float, (unsigned int)r.h << 16);
    r.l = bf16_rne(v - hf);
    return r;
}
__device__ __forceinline__ unsigned short f16bits(float v) {
    return __builtin_bit_cast(unsigned short, (_Float16)v);
}
// bijective XCD-chunked swizzle (m204)
__device__ __forceinline__ int xcd_swz(int orig, int nwg) {
    int q = nwg >> 3, r = nwg & 7;
    int x = orig & 7, p = orig >> 3;
    return (x < r ? x * (q + 1) : r * (q + 1) + (x - r) * q) + p;
}
__device__ __forceinline__ void gload16(const void* g, void* l) {
    __builtin_amdgcn_global_load_lds((const __attribute__((address_space(1))) void*)g,
                                     (__attribute__((address_space(3))) void*)l, 16, 0, 0);
}

// ---------------------------------------------------------------------------
#define N4_X  ((N_ * C_) / 4)
#define N4_W  ((3 * C_ * C_) / 4)
#define N4_PW ((C_ * C_) / 4)

__global__ __launch_bounds__(256)
void split_all(const float* __restrict__ x, const float* __restrict__ w,
               const float* __restrict__ pw,
               unsigned short* __restrict__ xhi, unsigned short* __restrict__ xlo,
               unsigned short* __restrict__ whi, unsigned short* __restrict__ wlo,
               unsigned short* __restrict__ pwhi, unsigned short* __restrict__ pwlo)
{
    int i = blockIdx.x * 256 + threadIdx.x;
    const float* src; unsigned short* dh; unsigned short* dl; int idx;
    if (i < N4_X)                { src = x;  dh = xhi;  dl = xlo;  idx = i; }
    else if (i < N4_X + N4_W)    { src = w;  dh = whi;  dl = wlo;  idx = i - N4_X; }
    else if (i < N4_X + N4_W + N4_PW) { src = pw; dh = pwhi; dl = pwlo; idx = i - N4_X - N4_W; }
    else return;
    float4 v = ((const float4*)src)[idx];
    HL a = split2(v.x), b = split2(v.y), c = split2(v.z), d = split2(v.w);
    ushort4v h, l;
    h.x = a.h; h.y = b.h; h.z = c.h; h.w = d.h;
    l.x = a.l; l.y = b.l; l.z = c.l; l.w = d.l;
    ((ushort4v*)dh)[idx] = h;
    ((ushort4v*)dl)[idx] = l;
}

// ---------------------------------------------------------------------------
// MFMA NT GEMM, split-2 bf16. Tile 64x64, BK=32, 4 waves (2x2), double-buffered.
// MODE 0: f32 out. MODE 1: QKV scatter; writes FP16 into q/k/v [h][N_][D_].
// ---------------------------------------------------------------------------
template<int MODE>
__global__ __launch_bounds__(256)
void gemm_mfma(const unsigned short* __restrict__ Ah, const unsigned short* __restrict__ Al,
               const unsigned short* __restrict__ Bh, const unsigned short* __restrict__ Bl,
               const float* __restrict__ bias, int M, int N,
               float* __restrict__ out0, float* __restrict__ out1, float* __restrict__ out2)
{
    __shared__ unsigned short Ash[2][2][64 * 32];
    __shared__ unsigned short Bsh[2][2][64 * 32];
    const int tid = threadIdx.x;
    const int lane = tid & 63;
    const int w = tid >> 6;

    const int wg = xcd_swz(blockIdx.x, gridDim.x);
    const int tmc = (M + 63) >> 6;
    const int tm = (wg % tmc) * 64;
    const int tn = (wg / tmc) * 64;

    const int wm = (w >> 1) * 32;
    const int wn = (w & 1) * 32;

    f32x4 acc[2][2] = {};

    const int lrow = lane >> 2;
    const int lcol = (lane & 3) * 8;
    int gmA = tm + w * 16 + lrow; if (gmA > M - 1) gmA = M - 1;
    const int gnB = tn + w * 16 + lrow;
    const size_t aoff = (size_t)gmA * 768 + lcol;
    const size_t boff = (size_t)gnB * 768 + lcol;

    auto STAGE = [&](int buf, int k0) {
        gload16(Ah + aoff + k0, &Ash[buf][0][w * 512]);
        gload16(Al + aoff + k0, &Ash[buf][1][w * 512]);
        gload16(Bh + boff + k0, &Bsh[buf][0][w * 512]);
        gload16(Bl + boff + k0, &Bsh[buf][1][w * 512]);
    };
    auto COMPUTE = [&](int buf) {
        const int fr = lane & 15;
        const int fk = (lane >> 4) * 8;
        bf16x8 ah[2], al[2], bh[2], bl[2];
        #pragma unroll
        for (int i = 0; i < 2; ++i) {
            ah[i] = *(const bf16x8*)&Ash[buf][0][(wm + i * 16 + fr) * 32 + fk];
            al[i] = *(const bf16x8*)&Ash[buf][1][(wm + i * 16 + fr) * 32 + fk];
            bh[i] = *(const bf16x8*)&Bsh[buf][0][(wn + i * 16 + fr) * 32 + fk];
            bl[i] = *(const bf16x8*)&Bsh[buf][1][(wn + i * 16 + fr) * 32 + fk];
        }
        #pragma unroll
        for (int mi = 0; mi < 2; ++mi)
            #pragma unroll
            for (int ni = 0; ni < 2; ++ni) {
                acc[mi][ni] = __builtin_amdgcn_mfma_f32_16x16x32_bf16(ah[mi], bh[ni], acc[mi][ni], 0, 0, 0);
                acc[mi][ni] = __builtin_amdgcn_mfma_f32_16x16x32_bf16(ah[mi], bl[ni], acc[mi][ni], 0, 0, 0);
                acc[mi][ni] = __builtin_amdgcn_mfma_f32_16x16x32_bf16(al[mi], bh[ni], acc[mi][ni], 0, 0, 0);
            }
    };

    STAGE(0, 0);
    __syncthreads();
    int cur = 0;
    for (int t = 0; t < 23; ++t) {
        STAGE(cur ^ 1, (t + 1) * 32);
        COMPUTE(cur);
        __syncthreads();
        cur ^= 1;
    }
    COMPUTE(cur);

    const int fr = lane & 15;
    const int fq = (lane >> 4) * 4;
    #pragma unroll
    for (int mi = 0; mi < 2; ++mi) {
        #pragma unroll
        for (int ni = 0; ni < 2; ++ni) {
            int n = tn + wn + ni * 16 + fr;
            float bb = bias[n];
            #pragma unroll
            for (int r = 0; r < 4; ++r) {
                int m = tm + wm + mi * 16 + fq + r;
                if (m >= M) continue;
                float val = acc[mi][ni][r] + bb;
                if (MODE == 0) {
                    out0[(size_t)m * N + n] = val;
                } else {
                    int which = n / C_;
                    int rr = n - which * C_;
                    int h = rr >> 6, d = rr & 63;
                    float* dst = (which == 0) ? out0 : (which == 1) ? out1 : out2;
                    ((unsigned short*)dst)[((size_t)h * N_ + m) * D_ + d] = f16bits(val);
                }
            }
        }
    }
}

// ---------------------------------------------------------------------------
// Unified attention partials, single-fp16 MFMA flash. LDS 16 KB.
// Blocks [0,1008): pano (3 chunks each, XCD swizzled). [1008,1320): spatial.
// Partials: fp32 o (unnormalized) + m + l per 64-row slot.
// ---------------------------------------------------------------------------
__global__ __launch_bounds__(256)
void attn_fused(const unsigned short* __restrict__ qp, const unsigned short* __restrict__ kp,
                const unsigned short* __restrict__ vp,
                float* __restrict__ po, float* __restrict__ pm, float* __restrict__ pl)
{
    __shared__ unsigned short Kl[64][64];   // fp16 K chunk, then reused for P
    __shared__ unsigned short VT[64][64];   // fp16 V^T chunk

    const int tid = threadIdx.x;
    const int lane = tid & 63;
    const int w = tid >> 6;
    const int wr = w * 16;
    const int c = lane & 15;
    const int g = lane >> 4;

    const bool is_pano = (blockIdx.x < NPANO);
    int h, vw = 0, p0 = 0, cv = 0, n0 = 0, ch_lo, ch_hi, slot;
    if (is_pano) {
        int wg = xcd_swz(blockIdx.x, NPANO);
        int third = wg % 3;
        int t = wg / 3;
        int pt = t % PTILES;
        int t2 = t / PTILES;
        vw = t2 & 3;
        h  = t2 >> 2;
        p0 = pt * TPP;
        cv = (vw + 1) & 3;
        ch_lo = third * 3;
        ch_hi = third * 3 + 3;
        slot = wg;
    } else {
        int id = blockIdx.x - NPANO;
        int sp = id % SPL;
        h = id / SPL;
        n0 = sp * 64;
        ch_lo = 0; ch_hi = 1;
        slot = NPANO + id;
    }

    // ---- persistent Q A-frags (fp16, direct) ----
    f16x8 qf[2];
    {
        int rowq;
        if (is_pano) { rowq = NS_ + vw * P_ + p0 + wr + c; if (rowq > N_ - 1) rowq = N_ - 1; }
        else         { rowq = wr + c; if (rowq > NS_ - 1) rowq = NS_ - 1; }
        const unsigned short* qrow = qp + (((size_t)h * N_ + rowq) << 6);
        qf[0] = *(const f16x8*)(qrow + g * 8);
        qf[1] = *(const f16x8*)(qrow + 32 + g * 8);
    }

    float m[4], l[4];
    f32x4 o[4] = {};
    #pragma unroll
    for (int r = 0; r < 4; ++r) { m[r] = -INFINITY; l[r] = 0.f; }

    for (int ch = ch_lo; ch < ch_hi; ++ch) {
        // ---- stage K [key][d^swz] (fp16, 8 elems/thread x2) ----
        #pragma unroll
        for (int i = 0; i < 2; ++i) {
            int f = i * 256 + tid;
            int key = f >> 3, d0 = (f & 7) << 3;
            int n;
            if (!is_pano) {
                n = n0 + key; if (n > N_ - 1) n = N_ - 1;
            } else if (ch < 7) {
                int sj = ch * 64 + key;
                n = (sj < NS_) ? sj : (NS_ + vw * P_ + (sj - NS_));
                if (sj >= NS_ + P_) n = 0;
            } else {
                int pp = p0 + (ch - 7) * 64 + key;
                if (pp >= P_) pp -= P_;
                if (pp >= P_) pp -= P_;
                n = NS_ + cv * P_ + pp;
            }
            uint4v kv = *(const uint4v*)(kp + (((size_t)h * N_ + n) << 6) + d0);
            *(uint4v*)&Kl[key][d0 ^ ((key & 7) << 3)] = kv;
        }
        // ---- stage V transposed [d][key^swz] (4x4 fp16 reg transpose) ----
        {
            int kg = (tid & 15) << 2;
            int dq = (tid >> 4) << 2;
            ushort4v rr[4];
            #pragma unroll
            for (int tt = 0; tt < 4; ++tt) {
                int key = kg + tt;
                int n;
                if (!is_pano) {
                    n = n0 + key; if (n > N_ - 1) n = N_ - 1;
                } else if (ch < 7) {
                    int sj = ch * 64 + key;
                    n = (sj < NS_) ? sj : (NS_ + vw * P_ + (sj - NS_));
                    if (sj >= NS_ + P_) n = 0;
                } else {
                    int pp = p0 + (ch - 7) * 64 + key;
                    if (pp >= P_) pp -= P_;
                    if (pp >= P_) pp -= P_;
                    n = NS_ + cv * P_ + pp;
                }
                rr[tt] = *(const ushort4v*)(vp + (((size_t)h * N_ + n) << 6) + dq);
            }
            #pragma unroll
            for (int j = 0; j < 4; ++j) {
                int d = dq + j;
                ushort4v wv;
                wv.x = rr[0][j]; wv.y = rr[1][j]; wv.z = rr[2][j]; wv.w = rr[3][j];
                *(ushort4v*)&VT[d][kg ^ ((d & 7) << 3)] = wv;
            }
        }
        __syncthreads();

        // ---- QK^T (1 MFMA per fragment pair) ----
        f32x4 s[4] = {};
        #pragma unroll
        for (int ss = 0; ss < 2; ++ss) {
            #pragma unroll
            for (int nf = 0; nf < 4; ++nf) {
                int key = nf * 16 + c;
                int dx = (ss * 32 + g * 8) ^ ((key & 7) << 3);
                f16x8 kf = *(const f16x8*)&Kl[key][dx];
                s[nf] = __builtin_amdgcn_mfma_f32_16x16x32_f16(qf[ss], kf, s[nf], 0, 0, 0);
            }
        }

        // ---- mask + scale ----
        #pragma unroll
        for (int nf = 0; nf < 4; ++nf) {
            int col = nf * 16 + c;
            #pragma unroll
            for (int r = 0; r < 4; ++r) {
                int rowl = wr + g * 4 + r;
                bool valid;
                if (!is_pano) {
                    valid = (n0 + col) < N_;
                } else if (ch < 7) {
                    valid = (ch * 64 + col) < (NS_ + P_);
                } else {
                    int i = (ch - 7) * 64 + col;
                    valid = (i < 127) && ((unsigned)(i - rowl) < 64u);
                }
                s[nf][r] = valid ? s[nf][r] * 0.125f : -INFINITY;
            }
        }

        // ---- online softmax ----
        float fct[4];
        #pragma unroll
        for (int r = 0; r < 4; ++r) {
            float cm = fmaxf(fmaxf(s[0][r], s[1][r]), fmaxf(s[2][r], s[3][r]));
            cm = fmaxf(cm, __shfl_xor(cm, 1, 64));
            cm = fmaxf(cm, __shfl_xor(cm, 2, 64));
            cm = fmaxf(cm, __shfl_xor(cm, 4, 64));
            cm = fmaxf(cm, __shfl_xor(cm, 8, 64));
            float nm = fmaxf(m[r], cm);
            fct[r] = __expf(m[r] - nm);
            m[r] = nm;
        }

        __syncthreads();   // all waves done reading Kl as K

        float ps[4] = {0.f, 0.f, 0.f, 0.f};
        #pragma unroll
        for (int nf = 0; nf < 4; ++nf) {
            #pragma unroll
            for (int r = 0; r < 4; ++r) {
                float p = __expf(s[nf][r] - m[r]);
                ps[r] += p;
                int rowl = wr + g * 4 + r;
                Kl[rowl][(nf * 16 + c) ^ ((rowl & 7) << 3)] = f16bits(p);
            }
        }
        #pragma unroll
        for (int r = 0; r < 4; ++r) {
            ps[r] += __shfl_xor(ps[r], 1, 64);
            ps[r] += __shfl_xor(ps[r], 2, 64);
            ps[r] += __shfl_xor(ps[r], 4, 64);
            ps[r] += __shfl_xor(ps[r], 8, 64);
            l[r] = l[r] * fct[r] + ps[r];
        }
        #pragma unroll
        for (int nf = 0; nf < 4; ++nf)
            #pragma unroll
            for (int r = 0; r < 4; ++r)
                o[nf][r] *= fct[r];

        // ---- P A-frags (wave-local rows, same-wave RAW) ----
        f16x8 pa[2];
        {
            int prow = wr + c;
            pa[0] = *(const f16x8*)&Kl[prow][(g * 8) ^ ((prow & 7) << 3)];
            pa[1] = *(const f16x8*)&Kl[prow][(32 + g * 8) ^ ((prow & 7) << 3)];
        }

        // ---- PV (1 MFMA per fragment pair) ----
        #pragma unroll
        for (int ss = 0; ss < 2; ++ss) {
            #pragma unroll
            for (int nf = 0; nf < 4; ++nf) {
                int d = nf * 16 + c;
                int kx = (ss * 32 + g * 8) ^ ((d & 7) << 3);
                f16x8 vf = *(const f16x8*)&VT[d][kx];
                o[nf] = __builtin_amdgcn_mfma_f32_16x16x32_f16(pa[ss], vf, o[nf], 0, 0, 0);
            }
        }
        __syncthreads();
    }

    // ---- write fp32 partials ----
    float* pob = po + (size_t)slot * 4096;
    #pragma unroll
    for (int r = 0; r < 4; ++r) {
        int rowl = wr + g * 4 + r;
        #pragma unroll
        for (int nf = 0; nf < 4; ++nf)
            pob[rowl * 64 + nf * 16 + c] = o[nf][r];
        if (c == 0) {
            pm[(size_t)slot * 64 + rowl] = m[r];
            pl[(size_t)slot * 64 + rowl] = l[r];
        }
    }
}

// ---------------------------------------------------------------------------
// Fused combine: blocks [0,336) pano (3 thirds), [336,396) spatial (26 splits).
// ---------------------------------------------------------------------------
__global__ __launch_bounds__(256)
void attn_comb(const float* __restrict__ po, const float* __restrict__ pm,
               const float* __restrict__ pl,
               unsigned short* __restrict__ atthi, unsigned short* __restrict__ attlo)
{
    const int b = blockIdx.x;
    const int tid = threadIdx.x;
    if (b < 336) {
        const int pt = b % PTILES;
        const int t2 = b / PTILES;
        const int vw = t2 & 3;
        const int h  = t2 >> 2;
        const int d = tid & 63;
        const int rg = tid >> 6;
        const int tb = b * 3;

        for (int i = 0; i < 16; ++i) {
            int row = rg * 16 + i;
            int prow = pt * 64 + row;
            if (prow >= P_) break;
            float m0 = pm[(size_t)tb * 64 + row],       l0 = pl[(size_t)tb * 64 + row];
            float m1 = pm[(size_t)(tb + 1) * 64 + row], l1 = pl[(size_t)(tb + 1) * 64 + row];
            float m2 = pm[(size_t)(tb + 2) * 64 + row], l2 = pl[(size_t)(tb + 2) * 64 + row];
            float M = fmaxf(fmaxf(m0, m1), m2);
            float w0 = __expf(m0 - M), w1 = __expf(m1 - M), w2 = __expf(m2 - M);
            float inv = 1.0f / (l0 * w0 + l1 * w1 + l2 * w2);
            float o0 = po[(size_t)tb * 4096 + row * 64 + d];
            float o1 = po[(size_t)(tb + 1) * 4096 + row * 64 + d];
            float o2 = po[(size_t)(tb + 2) * 4096 + row * 64 + d];
            float oo = (o0 * w0 + o1 * w1 + o2 * w2) * inv;
            HL hl = split2(oo);
            size_t idx = ((size_t)(NS_ + vw * P_ + prow)) * C_ + h * 64 + d;
            atthi[idx] = hl.h;
            attlo[idx] = hl.l;
        }
    } else {
        const int rid = (b - 336) * 4 + (tid >> 6);   // 0..239
        const int s = rid % NS_;
        const int h = rid / NS_;
        const int d = tid & 63;

        float M = -INFINITY;
        #pragma unroll 2
        for (int sp = 0; sp < SPL; ++sp)
            M = fmaxf(M, pm[(size_t)(NPANO + h * SPL + sp) * 64 + s]);
        float num = 0.f, den = 0.f;
        for (int sp = 0; sp < SPL; ++sp) {
            size_t sl = NPANO + h * SPL + sp;
            float w = __expf(pm[sl * 64 + s] - M);
            den = fmaf(pl[sl * 64 + s], w, den);
            num = fmaf(po[sl * 4096 + s * 64 + d], w, num);
        }
        HL hl = split2(num / den);
        size_t idx = (size_t)s * C_ + h * 64 + d;
        atthi[idx] = hl.h;
        attlo[idx] = hl.l;
    }
}

// ---------------------------------------------------------------------------
extern "C" void kernel_launch(void* const* d_in, const int* in_sizes, int n_in,
                              void* d_out, int out_size, void* d_ws, size_t ws_size,
                              hipStream_t stream)
{
    const float* x       = (const float*)d_in[0];
    const float* qkv_w   = (const float*)d_in[1];
    const float* qkv_b   = (const float*)d_in[2];
    const float* proj_w  = (const float*)d_in[3];
    const float* proj_b  = (const float*)d_in[4];
    float* out = (float*)d_out;

    const size_t per = (size_t)H_ * N_ * D_;
    unsigned short* qph = (unsigned short*)d_ws;       // fp16 q [h][n][d]
    unsigned short* kph = qph + per;
    unsigned short* vph = kph + per;
    unsigned short* xhi  = vph + per;
    unsigned short* xlo  = xhi + (size_t)N_ * C_;
    unsigned short* whi  = xlo + (size_t)N_ * C_;
    unsigned short* wlo  = whi + (size_t)3 * C_ * C_;
    unsigned short* pwhi = wlo + (size_t)3 * C_ * C_;
    unsigned short* pwlo = pwhi + (size_t)C_ * C_;
    unsigned short* atthi = pwlo + (size_t)C_ * C_;
    unsigned short* attlo = atthi + (size_t)N_ * C_;
    float* ppo = (float*)(attlo + (size_t)N_ * C_);
    float* ppm = ppo + (size_t)NPART * 4096;
    float* ppl = ppm + (size_t)NPART * 64;

    // 0) split GEMM inputs to bf16 hi/lo
    {
        int total = N4_X + N4_W + N4_PW;
        split_all<<<(total + 255) / 256, 256, 0, stream>>>(x, qkv_w, proj_w,
                                                           xhi, xlo, whi, wlo, pwhi, pwlo);
    }

    // 1) QKV projection (split-2 bf16 MFMA), fp16 q/k/v scatter
    gemm_mfma<1><<<26 * 36, 256, 0, stream>>>(xhi, xlo, whi, wlo, qkv_b, N_, 3 * C_,
                                              (float*)qph, (float*)kph, (float*)vph);

    // 2) unified attention partials (single-fp16 MFMA)
    attn_fused<<<NPART, 256, 0, stream>>>(qph, kph, vph, ppo, ppm, ppl);

    // 3) fused combine
    attn_comb<<<396, 256, 0, stream>>>(ppo, ppm, ppl, atthi, attlo);

    // 4) output projection (split-2 bf16 MFMA)
    gemm_mfma<0><<<26 * 12, 256, 0, stream>>>(atthi, attlo, pwhi, pwlo, proj_b, N_, C_, out, nullptr, nullptr);
}

// Round 15
// 93.683 us; speedup vs baseline: 1.2881x; 1.0420x over previous
//
#include <hip/hip_runtime.h>
#include <hip/hip_bf16.h>
#include <math.h>

#define H_  12
#define N_  1620
#define D_  64
#define C_  768
#define NS_ 20
#define V_  4
#define P_  400

#define TPP    64
#define PTILES 7    // ceil(400/64)
#define SPL    26   // spatial key splits of 64
#define NPANO  1008 // pano partial blocks: 336 tiles x 3 thirds
#define NPART  (NPANO + SPL * H_)   // 1320 total partial slots

typedef __bf16 bf16x8 __attribute__((ext_vector_type(8)));
typedef _Float16 f16x8 __attribute__((ext_vector_type(8)));
typedef float f32x4 __attribute__((ext_vector_type(4)));
typedef unsigned short ushort8 __attribute__((ext_vector_type(8)));
typedef unsigned short ushort4v __attribute__((ext_vector_type(4)));
typedef unsigned int uint4v __attribute__((ext_vector_type(4)));

struct HL { unsigned short h, l; };

__device__ __forceinline__ unsigned short bf16_rne(float v) {
    unsigned int u = __builtin_bit_cast(unsigned int, v);
    return (unsigned short)((u + 0x7fffu + ((u >> 16) & 1u)) >> 16);
}
__device__ __forceinline__ HL split2(float v) {
    HL r;
    r.h = bf16_rne(v);
    float hf = __builtin_bit_cast(float, (unsigned int)r.h << 16);
    r.l = bf16_rne(v - hf);
    return r;
}
__device__ __forceinline__ unsigned short f16bits(float v) {
    return __builtin_bit_cast(unsigned short, (_Float16)v);
}
__device__ __forceinline__ float f16val(unsigned short u) {
    return (float)__builtin_bit_cast(_Float16, u);
}
// bijective XCD-chunked swizzle (m204)
__device__ __forceinline__ int xcd_swz(int orig, int nwg) {
    int q = nwg >> 3, r = nwg & 7;
    int x = orig & 7, p = orig >> 3;
    return (x < r ? x * (q + 1) : r * (q + 1) + (x - r) * q) + p;
}
__device__ __forceinline__ void gload16(const void* g, void* l) {
    __builtin_amdgcn_global_load_lds((const __attribute__((address_space(1))) void*)g,
                                     (__attribute__((address_space(3))) void*)l, 16, 0, 0);
}

// ---------------------------------------------------------------------------
#define N4_X  ((N_ * C_) / 4)
#define N4_W  ((3 * C_ * C_) / 4)
#define N4_PW ((C_ * C_) / 4)

__global__ __launch_bounds__(256)
void split_all(const float* __restrict__ x, const float* __restrict__ w,
               const float* __restrict__ pw,
               unsigned short* __restrict__ xhi, unsigned short* __restrict__ xlo,
               unsigned short* __restrict__ whi, unsigned short* __restrict__ wlo,
               unsigned short* __restrict__ pwhi, unsigned short* __restrict__ pwlo)
{
    int i = blockIdx.x * 256 + threadIdx.x;
    const float* src; unsigned short* dh; unsigned short* dl; int idx;
    if (i < N4_X)                { src = x;  dh = xhi;  dl = xlo;  idx = i; }
    else if (i < N4_X + N4_W)    { src = w;  dh = whi;  dl = wlo;  idx = i - N4_X; }
    else if (i < N4_X + N4_W + N4_PW) { src = pw; dh = pwhi; dl = pwlo; idx = i - N4_X - N4_W; }
    else return;
    float4 v = ((const float4*)src)[idx];
    HL a = split2(v.x), b = split2(v.y), c = split2(v.z), d = split2(v.w);
    ushort4v h, l;
    h.x = a.h; h.y = b.h; h.z = c.h; h.w = d.h;
    l.x = a.l; l.y = b.l; l.z = c.l; l.w = d.l;
    ((ushort4v*)dh)[idx] = h;
    ((ushort4v*)dl)[idx] = l;
}

// ---------------------------------------------------------------------------
// MFMA NT GEMM, split-2 bf16. Tile 64x64, BK=32, 4 waves (2x2), double-buffered.
// MODE 0: f32 out. MODE 1: QKV scatter; writes FP16 into q/k/v [h][N_][D_].
// ---------------------------------------------------------------------------
template<int MODE>
__global__ __launch_bounds__(256)
void gemm_mfma(const unsigned short* __restrict__ Ah, const unsigned short* __restrict__ Al,
               const unsigned short* __restrict__ Bh, const unsigned short* __restrict__ Bl,
               const float* __restrict__ bias, int M, int N,
               float* __restrict__ out0, float* __restrict__ out1, float* __restrict__ out2)
{
    __shared__ unsigned short Ash[2][2][64 * 32];
    __shared__ unsigned short Bsh[2][2][64 * 32];
    const int tid = threadIdx.x;
    const int lane = tid & 63;
    const int w = tid >> 6;

    const int wg = xcd_swz(blockIdx.x, gridDim.x);
    const int tmc = (M + 63) >> 6;
    const int tm = (wg % tmc) * 64;
    const int tn = (wg / tmc) * 64;

    const int wm = (w >> 1) * 32;
    const int wn = (w & 1) * 32;

    f32x4 acc[2][2] = {};

    const int lrow = lane >> 2;
    const int lcol = (lane & 3) * 8;
    int gmA = tm + w * 16 + lrow; if (gmA > M - 1) gmA = M - 1;
    const int gnB = tn + w * 16 + lrow;
    const size_t aoff = (size_t)gmA * 768 + lcol;
    const size_t boff = (size_t)gnB * 768 + lcol;

    auto STAGE = [&](int buf, int k0) {
        gload16(Ah + aoff + k0, &Ash[buf][0][w * 512]);
        gload16(Al + aoff + k0, &Ash[buf][1][w * 512]);
        gload16(Bh + boff + k0, &Bsh[buf][0][w * 512]);
        gload16(Bl + boff + k0, &Bsh[buf][1][w * 512]);
    };
    auto COMPUTE = [&](int buf) {
        const int fr = lane & 15;
        const int fk = (lane >> 4) * 8;
        bf16x8 ah[2], al[2], bh[2], bl[2];
        #pragma unroll
        for (int i = 0; i < 2; ++i) {
            ah[i] = *(const bf16x8*)&Ash[buf][0][(wm + i * 16 + fr) * 32 + fk];
            al[i] = *(const bf16x8*)&Ash[buf][1][(wm + i * 16 + fr) * 32 + fk];
            bh[i] = *(const bf16x8*)&Bsh[buf][0][(wn + i * 16 + fr) * 32 + fk];
            bl[i] = *(const bf16x8*)&Bsh[buf][1][(wn + i * 16 + fr) * 32 + fk];
        }
        #pragma unroll
        for (int mi = 0; mi < 2; ++mi)
            #pragma unroll
            for (int ni = 0; ni < 2; ++ni) {
                acc[mi][ni] = __builtin_amdgcn_mfma_f32_16x16x32_bf16(ah[mi], bh[ni], acc[mi][ni], 0, 0, 0);
                acc[mi][ni] = __builtin_amdgcn_mfma_f32_16x16x32_bf16(ah[mi], bl[ni], acc[mi][ni], 0, 0, 0);
                acc[mi][ni] = __builtin_amdgcn_mfma_f32_16x16x32_bf16(al[mi], bh[ni], acc[mi][ni], 0, 0, 0);
            }
    };

    STAGE(0, 0);
    __syncthreads();
    int cur = 0;
    for (int t = 0; t < 23; ++t) {
        STAGE(cur ^ 1, (t + 1) * 32);
        COMPUTE(cur);
        __syncthreads();
        cur ^= 1;
    }
    COMPUTE(cur);

    const int fr = lane & 15;
    const int fq = (lane >> 4) * 4;
    #pragma unroll
    for (int mi = 0; mi < 2; ++mi) {
        #pragma unroll
        for (int ni = 0; ni < 2; ++ni) {
            int n = tn + wn + ni * 16 + fr;
            float bb = bias[n];
            #pragma unroll
            for (int r = 0; r < 4; ++r) {
                int m = tm + wm + mi * 16 + fq + r;
                if (m >= M) continue;
                float val = acc[mi][ni][r] + bb;
                if (MODE == 0) {
                    out0[(size_t)m * N + n] = val;
                } else {
                    int which = n / C_;
                    int rr = n - which * C_;
                    int h = rr >> 6, d = rr & 63;
                    float* dst = (which == 0) ? out0 : (which == 1) ? out1 : out2;
                    ((unsigned short*)dst)[((size_t)h * N_ + m) * D_ + d] = f16bits(val);
                }
            }
        }
    }
}

// ---------------------------------------------------------------------------
// Unified attention partials, single-fp16 MFMA flash, double-buffered chunks.
// LDS: K[2]+V[2] (8 KB each) + wave-local P (8 KB) = 40 KB. One barrier per
// chunk. K staged via PRE-SWIZZLED global_load_lds (linear dest, XOR'd src).
// Blocks [0,1008): pano (3 chunks, XCD swizzled). [1008,1320): spatial.
// Partials fp16 o + fp32 m,l.
// ---------------------------------------------------------------------------
__global__ __launch_bounds__(256)
void attn_fused(const unsigned short* __restrict__ qp, const unsigned short* __restrict__ kp,
                const unsigned short* __restrict__ vp,
                unsigned short* __restrict__ po, float* __restrict__ pm, float* __restrict__ pl)
{
    __shared__ unsigned short Kf[2][64][64];
    __shared__ unsigned short Vf[2][64][64];
    __shared__ unsigned short Pf[64][64];

    const int tid = threadIdx.x;
    const int lane = tid & 63;
    const int w = tid >> 6;
    const int wr = w * 16;
    const int c = lane & 15;
    const int g = lane >> 4;

    const bool is_pano = (blockIdx.x < NPANO);
    int h, vw = 0, p0 = 0, cv = 0, n0 = 0, ch_lo, ch_hi, slot;
    if (is_pano) {
        int wg = xcd_swz(blockIdx.x, NPANO);
        int third = wg % 3;
        int t = wg / 3;
        int pt = t % PTILES;
        int t2 = t / PTILES;
        vw = t2 & 3;
        h  = t2 >> 2;
        p0 = pt * TPP;
        cv = (vw + 1) & 3;
        ch_lo = third * 3;
        ch_hi = third * 3 + 3;
        slot = wg;
    } else {
        int id = blockIdx.x - NPANO;
        int sp = id % SPL;
        h = id / SPL;
        n0 = sp * 64;
        ch_lo = 0; ch_hi = 1;
        slot = NPANO + id;
    }

    auto keyrow = [&](int ch, int key) -> int {
        int n;
        if (!is_pano) {
            n = n0 + key; if (n > N_ - 1) n = N_ - 1;
        } else if (ch < 7) {
            int sj = ch * 64 + key;
            n = (sj < NS_) ? sj : (NS_ + vw * P_ + (sj - NS_));
            if (sj >= NS_ + P_) n = 0;
        } else {
            int pp = p0 + (ch - 7) * 64 + key;
            if (pp >= P_) pp -= P_;
            if (pp >= P_) pp -= P_;
            n = NS_ + cv * P_ + pp;
        }
        return n;
    };

    // K stage: 2 gload16/wave; linear LDS dest, pre-swizzled global src.
    auto stage_k = [&](int buf, int ch) {
        #pragma unroll
        for (int t = 0; t < 2; ++t) {
            int key = wr + t * 8 + (lane >> 3);
            int n = keyrow(ch, key);
            int dsrc = ((lane & 7) ^ (key & 7)) << 3;
            gload16(kp + (((size_t)h * N_ + n) << 6) + dsrc, &Kf[buf][wr + t * 8][0]);
        }
    };
    // V load to regs (issue early)
    auto vload = [&](ushort4v* rr, int ch) {
        int kg = (tid & 15) << 2;
        int dq = (tid >> 4) << 2;
        #pragma unroll
        for (int tt = 0; tt < 4; ++tt) {
            int n = keyrow(ch, kg + tt);
            rr[tt] = *(const ushort4v*)(vp + (((size_t)h * N_ + n) << 6) + dq);
        }
    };
    // V transpose + swizzled LDS write (late)
    auto vwrite = [&](int buf, const ushort4v* rr) {
        int kg = (tid & 15) << 2;
        int dq = (tid >> 4) << 2;
        #pragma unroll
        for (int j = 0; j < 4; ++j) {
            int d = dq + j;
            ushort4v wv;
            wv.x = rr[0][j]; wv.y = rr[1][j]; wv.z = rr[2][j]; wv.w = rr[3][j];
            *(ushort4v*)&Vf[buf][d][kg ^ ((d & 7) << 3)] = wv;
        }
    };

    // ---- persistent Q A-frags ----
    f16x8 qf[2];
    {
        int rowq;
        if (is_pano) { rowq = NS_ + vw * P_ + p0 + wr + c; if (rowq > N_ - 1) rowq = N_ - 1; }
        else         { rowq = wr + c; if (rowq > NS_ - 1) rowq = NS_ - 1; }
        const unsigned short* qrow = qp + (((size_t)h * N_ + rowq) << 6);
        qf[0] = *(const f16x8*)(qrow + g * 8);
        qf[1] = *(const f16x8*)(qrow + 32 + g * 8);
    }

    float m[4], l[4];
    f32x4 o[4] = {};
    #pragma unroll
    for (int r = 0; r < 4; ++r) { m[r] = -INFINITY; l[r] = 0.f; }

    // ---- prologue: stage first chunk ----
    ushort4v vr[4];
    stage_k(0, ch_lo);
    vload(vr, ch_lo);
    vwrite(0, vr);
    __syncthreads();

    int buf = 0;
    for (int ch = ch_lo; ch < ch_hi; ++ch) {
        const bool pre = (ch + 1 < ch_hi);
        if (pre) {
            stage_k(buf ^ 1, ch + 1);   // async into other buffer
            vload(vr, ch + 1);          // issue V loads early
        }

        // ---- QK^T on Kf[buf] ----
        f32x4 s[4] = {};
        #pragma unroll
        for (int ss = 0; ss < 2; ++ss) {
            #pragma unroll
            for (int nf = 0; nf < 4; ++nf) {
                int key = nf * 16 + c;
                int dx = (ss * 32 + g * 8) ^ ((key & 7) << 3);
                f16x8 kf = *(const f16x8*)&Kf[buf][key][dx];
                s[nf] = __builtin_amdgcn_mfma_f32_16x16x32_f16(qf[ss], kf, s[nf], 0, 0, 0);
            }
        }

        // ---- mask + scale ----
        #pragma unroll
        for (int nf = 0; nf < 4; ++nf) {
            int col = nf * 16 + c;
            #pragma unroll
            for (int r = 0; r < 4; ++r) {
                int rowl = wr + g * 4 + r;
                bool valid;
                if (!is_pano) {
                    valid = (n0 + col) < N_;
                } else if (ch < 7) {
                    valid = (ch * 64 + col) < (NS_ + P_);
                } else {
                    int i = (ch - 7) * 64 + col;
                    valid = (i < 127) && ((unsigned)(i - rowl) < 64u);
                }
                s[nf][r] = valid ? s[nf][r] * 0.125f : -INFINITY;
            }
        }

        // ---- online softmax ----
        float fct[4];
        #pragma unroll
        for (int r = 0; r < 4; ++r) {
            float cm = fmaxf(fmaxf(s[0][r], s[1][r]), fmaxf(s[2][r], s[3][r]));
            cm = fmaxf(cm, __shfl_xor(cm, 1, 64));
            cm = fmaxf(cm, __shfl_xor(cm, 2, 64));
            cm = fmaxf(cm, __shfl_xor(cm, 4, 64));
            cm = fmaxf(cm, __shfl_xor(cm, 8, 64));
            float nm = fmaxf(m[r], cm);
            fct[r] = __expf(m[r] - nm);
            m[r] = nm;
        }

        // ---- P into wave-local Pf (no barrier: same-wave LDS RAW) ----
        float ps[4] = {0.f, 0.f, 0.f, 0.f};
        #pragma unroll
        for (int nf = 0; nf < 4; ++nf) {
            #pragma unroll
            for (int r = 0; r < 4; ++r) {
                float p = __expf(s[nf][r] - m[r]);
                ps[r] += p;
                int rowl = wr + g * 4 + r;
                Pf[rowl][(nf * 16 + c) ^ ((rowl & 7) << 3)] = f16bits(p);
            }
        }
        #pragma unroll
        for (int r = 0; r < 4; ++r) {
            ps[r] += __shfl_xor(ps[r], 1, 64);
            ps[r] += __shfl_xor(ps[r], 2, 64);
            ps[r] += __shfl_xor(ps[r], 4, 64);
            ps[r] += __shfl_xor(ps[r], 8, 64);
            l[r] = l[r] * fct[r] + ps[r];
        }
        #pragma unroll
        for (int nf = 0; nf < 4; ++nf)
            #pragma unroll
            for (int r = 0; r < 4; ++r)
                o[nf][r] *= fct[r];

        // ---- P A-frags (wave-local rows) ----
        f16x8 pa[2];
        {
            int prow = wr + c;
            pa[0] = *(const f16x8*)&Pf[prow][(g * 8) ^ ((prow & 7) << 3)];
            pa[1] = *(const f16x8*)&Pf[prow][(32 + g * 8) ^ ((prow & 7) << 3)];
        }

        // ---- PV on Vf[buf] ----
        #pragma unroll
        for (int ss = 0; ss < 2; ++ss) {
            #pragma unroll
            for (int nf = 0; nf < 4; ++nf) {
                int d = nf * 16 + c;
                int kx = (ss * 32 + g * 8) ^ ((d & 7) << 3);
                f16x8 vf = *(const f16x8*)&Vf[buf][d][kx];
                o[nf] = __builtin_amdgcn_mfma_f32_16x16x32_f16(pa[ss], vf, o[nf], 0, 0, 0);
            }
        }

        if (pre) vwrite(buf ^ 1, vr);   // land V after compute (T14 split)
        __syncthreads();                // drains gload + ds_writes; next buf ready
        buf ^= 1;
    }

    // ---- write fp16 partials (skip dead spatial rows) ----
    unsigned short* pob = po + (size_t)slot * 4096;
    #pragma unroll
    for (int r = 0; r < 4; ++r) {
        int rowl = wr + g * 4 + r;
        if (!is_pano && rowl >= NS_) continue;
        #pragma unroll
        for (int nf = 0; nf < 4; ++nf)
            pob[rowl * 64 + nf * 16 + c] = f16bits(o[nf][r]);
        if (c == 0) {
            pm[(size_t)slot * 64 + rowl] = m[r];
            pl[(size_t)slot * 64 + rowl] = l[r];
        }
    }
}

// ---------------------------------------------------------------------------
// Fused combine: blocks [0,336) pano (3 thirds), [336,396) spatial (26 splits).
// ---------------------------------------------------------------------------
__global__ __launch_bounds__(256)
void attn_comb(const unsigned short* __restrict__ po, const float* __restrict__ pm,
               const float* __restrict__ pl,
               unsigned short* __restrict__ atthi, unsigned short* __restrict__ attlo)
{
    const int b = blockIdx.x;
    const int tid = threadIdx.x;
    if (b < 336) {
        const int pt = b % PTILES;
        const int t2 = b / PTILES;
        const int vw = t2 & 3;
        const int h  = t2 >> 2;
        const int d = tid & 63;
        const int rg = tid >> 6;
        const int tb = b * 3;

        for (int i = 0; i < 16; ++i) {
            int row = rg * 16 + i;
            int prow = pt * 64 + row;
            if (prow >= P_) break;
            float m0 = pm[(size_t)tb * 64 + row],       l0 = pl[(size_t)tb * 64 + row];
            float m1 = pm[(size_t)(tb + 1) * 64 + row], l1 = pl[(size_t)(tb + 1) * 64 + row];
            float m2 = pm[(size_t)(tb + 2) * 64 + row], l2 = pl[(size_t)(tb + 2) * 64 + row];
            float M = fmaxf(fmaxf(m0, m1), m2);
            float w0 = __expf(m0 - M), w1 = __expf(m1 - M), w2 = __expf(m2 - M);
            float inv = 1.0f / (l0 * w0 + l1 * w1 + l2 * w2);
            float o0 = f16val(po[(size_t)tb * 4096 + row * 64 + d]);
            float o1 = f16val(po[(size_t)(tb + 1) * 4096 + row * 64 + d]);
            float o2 = f16val(po[(size_t)(tb + 2) * 4096 + row * 64 + d]);
            float oo = (o0 * w0 + o1 * w1 + o2 * w2) * inv;
            HL hl = split2(oo);
            size_t idx = ((size_t)(NS_ + vw * P_ + prow)) * C_ + h * 64 + d;
            atthi[idx] = hl.h;
            attlo[idx] = hl.l;
        }
    } else {
        const int rid = (b - 336) * 4 + (tid >> 6);   // 0..239
        const int s = rid % NS_;
        const int h = rid / NS_;
        const int d = tid & 63;

        float M = -INFINITY;
        #pragma unroll 2
        for (int sp = 0; sp < SPL; ++sp)
            M = fmaxf(M, pm[(size_t)(NPANO + h * SPL + sp) * 64 + s]);
        float num = 0.f, den = 0.f;
        for (int sp = 0; sp < SPL; ++sp) {
            size_t sl = NPANO + h * SPL + sp;
            float w = __expf(pm[sl * 64 + s] - M);
            den = fmaf(pl[sl * 64 + s], w, den);
            num = fmaf(f16val(po[sl * 4096 + s * 64 + d]), w, num);
        }
        HL hl = split2(num / den);
        size_t idx = (size_t)s * C_ + h * 64 + d;
        atthi[idx] = hl.h;
        attlo[idx] = hl.l;
    }
}

// ---------------------------------------------------------------------------
extern "C" void kernel_launch(void* const* d_in, const int* in_sizes, int n_in,
                              void* d_out, int out_size, void* d_ws, size_t ws_size,
                              hipStream_t stream)
{
    const float* x       = (const float*)d_in[0];
    const float* qkv_w   = (const float*)d_in[1];
    const float* qkv_b   = (const float*)d_in[2];
    const float* proj_w  = (const float*)d_in[3];
    const float* proj_b  = (const float*)d_in[4];
    float* out = (float*)d_out;

    const size_t per = (size_t)H_ * N_ * D_;
    unsigned short* qph = (unsigned short*)d_ws;       // fp16 q [h][n][d]
    unsigned short* kph = qph + per;
    unsigned short* vph = kph + per;
    unsigned short* xhi  = vph + per;
    unsigned short* xlo  = xhi + (size_t)N_ * C_;
    unsigned short* whi  = xlo + (size_t)N_ * C_;
    unsigned short* wlo  = whi + (size_t)3 * C_ * C_;
    unsigned short* pwhi = wlo + (size_t)3 * C_ * C_;
    unsigned short* pwlo = pwhi + (size_t)C_ * C_;
    unsigned short* atthi = pwlo + (size_t)C_ * C_;
    unsigned short* attlo = atthi + (size_t)N_ * C_;
    unsigned short* ppo = attlo + (size_t)N_ * C_;     // fp16 partials
    float* ppm = (float*)(ppo + (size_t)NPART * 4096);
    float* ppl = ppm + (size_t)NPART * 64;

    // 0) split GEMM inputs to bf16 hi/lo
    {
        int total = N4_X + N4_W + N4_PW;
        split_all<<<(total + 255) / 256, 256, 0, stream>>>(x, qkv_w, proj_w,
                                                           xhi, xlo, whi, wlo, pwhi, pwlo);
    }

    // 1) QKV projection (split-2 bf16 MFMA), fp16 q/k/v scatter
    gemm_mfma<1><<<26 * 36, 256, 0, stream>>>(xhi, xlo, whi, wlo, qkv_b, N_, 3 * C_,
                                              (float*)qph, (float*)kph, (float*)vph);

    // 2) unified attention partials (single-fp16 MFMA, dbuf chunks)
    attn_fused<<<NPART, 256, 0, stream>>>(qph, kph, vph, ppo, ppm, ppl);

    // 3) fused combine
    attn_comb<<<396, 256, 0, stream>>>(ppo, ppm, ppl, atthi, attlo);

    // 4) output projection (split-2 bf16 MFMA)
    gemm_mfma<0><<<26 * 12, 256, 0, stream>>>(atthi, attlo, pwhi, pwlo, proj_b, N_, C_, out, nullptr, nullptr);
}

// Round 16
// 67.945 us; speedup vs baseline: 1.7760x; 1.3788x over previous
//
#include <hip/hip_runtime.h>
#include <hip/hip_bf16.h>
#include <math.h>

#define H_  12
#define N_  1620
#define D_  64
#define C_  768
#define NS_ 20
#define V_  4
#define P_  400

#define TPP    64
#define PTILES 7    // ceil(400/64)
#define SPL    26   // spatial key splits of 64
#define NPANO  1008 // pano partial blocks: 336 tiles x 3 thirds
#define NPART  (NPANO + SPL * H_)   // 1320 total partial slots

typedef _Float16 f16x8 __attribute__((ext_vector_type(8)));
typedef float f32x4 __attribute__((ext_vector_type(4)));
typedef unsigned short ushort4v __attribute__((ext_vector_type(4)));
typedef unsigned int uint4v __attribute__((ext_vector_type(4)));

__device__ __forceinline__ unsigned short f16bits(float v) {
    return __builtin_bit_cast(unsigned short, (_Float16)v);
}
__device__ __forceinline__ float f16val(unsigned short u) {
    return (float)__builtin_bit_cast(_Float16, u);
}
// bijective XCD-chunked swizzle (m204)
__device__ __forceinline__ int xcd_swz(int orig, int nwg) {
    int q = nwg >> 3, r = nwg & 7;
    int x = orig & 7, p = orig >> 3;
    return (x < r ? x * (q + 1) : r * (q + 1) + (x - r) * q) + p;
}
__device__ __forceinline__ void gload16(const void* g, void* l) {
    __builtin_amdgcn_global_load_lds((const __attribute__((address_space(1))) void*)g,
                                     (__attribute__((address_space(3))) void*)l, 16, 0, 0);
}

// ---------------------------------------------------------------------------
#define N4_X  ((N_ * C_) / 4)
#define N4_W  ((3 * C_ * C_) / 4)
#define N4_PW ((C_ * C_) / 4)

__global__ __launch_bounds__(256)
void cvt_all(const float* __restrict__ x, const float* __restrict__ w,
             const float* __restrict__ pw,
             unsigned short* __restrict__ xf, unsigned short* __restrict__ wf,
             unsigned short* __restrict__ pwf)
{
    int i = blockIdx.x * 256 + threadIdx.x;
    const float* src; unsigned short* dst; int idx;
    if (i < N4_X)                { src = x;  dst = xf;  idx = i; }
    else if (i < N4_X + N4_W)    { src = w;  dst = wf;  idx = i - N4_X; }
    else if (i < N4_X + N4_W + N4_PW) { src = pw; dst = pwf; idx = i - N4_X - N4_W; }
    else return;
    float4 v = ((const float4*)src)[idx];
    ushort4v o;
    o.x = f16bits(v.x); o.y = f16bits(v.y); o.z = f16bits(v.z); o.w = f16bits(v.w);
    ((ushort4v*)dst)[idx] = o;
}

// ---------------------------------------------------------------------------
// Single-fp16 MFMA NT GEMM. Tile 64x64, BK=64, 4 waves (2x2, each 32x32),
// double-buffered; staging via pre-swizzled global_load_lds (linear dest,
// XOR'd global k-block); reads use the same XOR (2-way conflicts max).
// MODE 0: f32 out. MODE 1: QKV scatter; writes fp16 q/k/v [h][N_][D_].
// ---------------------------------------------------------------------------
template<int MODE>
__global__ __launch_bounds__(256)
void gemm_f16(const unsigned short* __restrict__ A, const unsigned short* __restrict__ B,
              const float* __restrict__ bias, int M, int N,
              float* __restrict__ out0, float* __restrict__ out1, float* __restrict__ out2)
{
    __shared__ unsigned short Ash[2][64][64];
    __shared__ unsigned short Bsh[2][64][64];
    const int tid = threadIdx.x;
    const int lane = tid & 63;
    const int w = tid >> 6;
    const int c = lane & 15;
    const int g = lane >> 4;

    const int wg = xcd_swz(blockIdx.x, gridDim.x);
    const int tmc = (M + 63) >> 6;
    const int tm = (wg % tmc) * 64;
    const int tn = (wg / tmc) * 64;

    const int wm = (w >> 1) * 32;
    const int wn = (w & 1) * 32;

    f32x4 acc[2][2] = {};

    // staging geometry: wave w, load t covers rows w*16+t*8 .. +7;
    // lane L -> row +(L>>3), k-block (L&7)*8 (linear dest). Pre-swizzle the
    // GLOBAL k-block by row&7 = L>>3 so LDS holds swizzled content.
    const int srow = lane >> 3;
    const int ksrc = (((lane & 7) ^ srow) << 3);
    int gmA = tm + w * 16 + srow;       // + t*8 added per load
    const int gnB = tn + w * 16 + srow;

    auto STAGE = [&](int buf, int k0) {
        #pragma unroll
        for (int t = 0; t < 2; ++t) {
            int gm = gmA + t * 8; if (gm > M - 1) gm = M - 1;
            gload16(A + (size_t)gm * 768 + k0 + ksrc, &Ash[buf][w * 16 + t * 8][0]);
            gload16(B + (size_t)(gnB + t * 8) * 768 + k0 + ksrc, &Bsh[buf][w * 16 + t * 8][0]);
        }
    };
    auto COMPUTE = [&](int buf) {
        #pragma unroll
        for (int ss = 0; ss < 2; ++ss) {
            f16x8 af[2], bf[2];
            #pragma unroll
            for (int i = 0; i < 2; ++i) {
                int ra = wm + i * 16 + c;
                af[i] = *(const f16x8*)&Ash[buf][ra][(ss * 32 + g * 8) ^ ((ra & 7) << 3)];
                int rb = wn + i * 16 + c;
                bf[i] = *(const f16x8*)&Bsh[buf][rb][(ss * 32 + g * 8) ^ ((rb & 7) << 3)];
            }
            #pragma unroll
            for (int mi = 0; mi < 2; ++mi)
                #pragma unroll
                for (int ni = 0; ni < 2; ++ni)
                    acc[mi][ni] = __builtin_amdgcn_mfma_f32_16x16x32_f16(af[mi], bf[ni], acc[mi][ni], 0, 0, 0);
        }
    };

    STAGE(0, 0);
    __syncthreads();
    int cur = 0;
    for (int t = 0; t < 11; ++t) {
        STAGE(cur ^ 1, (t + 1) * 64);
        COMPUTE(cur);
        __syncthreads();
        cur ^= 1;
    }
    COMPUTE(cur);

    const int fq = g * 4;
    #pragma unroll
    for (int mi = 0; mi < 2; ++mi) {
        #pragma unroll
        for (int ni = 0; ni < 2; ++ni) {
            int n = tn + wn + ni * 16 + c;
            float bb = bias[n];
            #pragma unroll
            for (int r = 0; r < 4; ++r) {
                int m = tm + wm + mi * 16 + fq + r;
                if (m >= M) continue;
                float val = acc[mi][ni][r] + bb;
                if (MODE == 0) {
                    out0[(size_t)m * N + n] = val;
                } else {
                    int which = n / C_;
                    int rr = n - which * C_;
                    int h = rr >> 6, d = rr & 63;
                    float* dst = (which == 0) ? out0 : (which == 1) ? out1 : out2;
                    ((unsigned short*)dst)[((size_t)h * N_ + m) * D_ + d] = f16bits(val);
                }
            }
        }
    }
}

// ---------------------------------------------------------------------------
// Unified attention partials, single-fp16 MFMA flash, double-buffered chunks.
// LDS: K[2]+V[2] (8 KB each) + wave-local P (8 KB) = 40 KB. One barrier per
// chunk. Blocks [0,1008): pano (3 chunks, XCD swizzled). [1008,1320): spatial.
// Partials fp16 o + fp32 m,l.
// ---------------------------------------------------------------------------
__global__ __launch_bounds__(256)
void attn_fused(const unsigned short* __restrict__ qp, const unsigned short* __restrict__ kp,
                const unsigned short* __restrict__ vp,
                unsigned short* __restrict__ po, float* __restrict__ pm, float* __restrict__ pl)
{
    __shared__ unsigned short Kf[2][64][64];
    __shared__ unsigned short Vf[2][64][64];
    __shared__ unsigned short Pf[64][64];

    const int tid = threadIdx.x;
    const int lane = tid & 63;
    const int w = tid >> 6;
    const int wr = w * 16;
    const int c = lane & 15;
    const int g = lane >> 4;

    const bool is_pano = (blockIdx.x < NPANO);
    int h, vw = 0, p0 = 0, cv = 0, n0 = 0, ch_lo, ch_hi, slot;
    if (is_pano) {
        int wg = xcd_swz(blockIdx.x, NPANO);
        int third = wg % 3;
        int t = wg / 3;
        int pt = t % PTILES;
        int t2 = t / PTILES;
        vw = t2 & 3;
        h  = t2 >> 2;
        p0 = pt * TPP;
        cv = (vw + 1) & 3;
        ch_lo = third * 3;
        ch_hi = third * 3 + 3;
        slot = wg;
    } else {
        int id = blockIdx.x - NPANO;
        int sp = id % SPL;
        h = id / SPL;
        n0 = sp * 64;
        ch_lo = 0; ch_hi = 1;
        slot = NPANO + id;
    }

    auto keyrow = [&](int ch, int key) -> int {
        int n;
        if (!is_pano) {
            n = n0 + key; if (n > N_ - 1) n = N_ - 1;
        } else if (ch < 7) {
            int sj = ch * 64 + key;
            n = (sj < NS_) ? sj : (NS_ + vw * P_ + (sj - NS_));
            if (sj >= NS_ + P_) n = 0;
        } else {
            int pp = p0 + (ch - 7) * 64 + key;
            if (pp >= P_) pp -= P_;
            if (pp >= P_) pp -= P_;
            n = NS_ + cv * P_ + pp;
        }
        return n;
    };

    auto stage_k = [&](int buf, int ch) {
        #pragma unroll
        for (int t = 0; t < 2; ++t) {
            int key = wr + t * 8 + (lane >> 3);
            int n = keyrow(ch, key);
            int dsrc = ((lane & 7) ^ (key & 7)) << 3;
            gload16(kp + (((size_t)h * N_ + n) << 6) + dsrc, &Kf[buf][wr + t * 8][0]);
        }
    };
    auto vload = [&](ushort4v* rr, int ch) {
        int kg = (tid & 15) << 2;
        int dq = (tid >> 4) << 2;
        #pragma unroll
        for (int tt = 0; tt < 4; ++tt) {
            int n = keyrow(ch, kg + tt);
            rr[tt] = *(const ushort4v*)(vp + (((size_t)h * N_ + n) << 6) + dq);
        }
    };
    auto vwrite = [&](int buf, const ushort4v* rr) {
        int kg = (tid & 15) << 2;
        int dq = (tid >> 4) << 2;
        #pragma unroll
        for (int j = 0; j < 4; ++j) {
            int d = dq + j;
            ushort4v wv;
            wv.x = rr[0][j]; wv.y = rr[1][j]; wv.z = rr[2][j]; wv.w = rr[3][j];
            *(ushort4v*)&Vf[buf][d][kg ^ ((d & 7) << 3)] = wv;
        }
    };

    f16x8 qf[2];
    {
        int rowq;
        if (is_pano) { rowq = NS_ + vw * P_ + p0 + wr + c; if (rowq > N_ - 1) rowq = N_ - 1; }
        else         { rowq = wr + c; if (rowq > NS_ - 1) rowq = NS_ - 1; }
        const unsigned short* qrow = qp + (((size_t)h * N_ + rowq) << 6);
        qf[0] = *(const f16x8*)(qrow + g * 8);
        qf[1] = *(const f16x8*)(qrow + 32 + g * 8);
    }

    float m[4], l[4];
    f32x4 o[4] = {};
    #pragma unroll
    for (int r = 0; r < 4; ++r) { m[r] = -INFINITY; l[r] = 0.f; }

    ushort4v vr[4];
    stage_k(0, ch_lo);
    vload(vr, ch_lo);
    vwrite(0, vr);
    __syncthreads();

    int buf = 0;
    for (int ch = ch_lo; ch < ch_hi; ++ch) {
        const bool pre = (ch + 1 < ch_hi);
        if (pre) {
            stage_k(buf ^ 1, ch + 1);
            vload(vr, ch + 1);
        }

        f32x4 s[4] = {};
        #pragma unroll
        for (int ss = 0; ss < 2; ++ss) {
            #pragma unroll
            for (int nf = 0; nf < 4; ++nf) {
                int key = nf * 16 + c;
                int dx = (ss * 32 + g * 8) ^ ((key & 7) << 3);
                f16x8 kf = *(const f16x8*)&Kf[buf][key][dx];
                s[nf] = __builtin_amdgcn_mfma_f32_16x16x32_f16(qf[ss], kf, s[nf], 0, 0, 0);
            }
        }

        #pragma unroll
        for (int nf = 0; nf < 4; ++nf) {
            int col = nf * 16 + c;
            #pragma unroll
            for (int r = 0; r < 4; ++r) {
                int rowl = wr + g * 4 + r;
                bool valid;
                if (!is_pano) {
                    valid = (n0 + col) < N_;
                } else if (ch < 7) {
                    valid = (ch * 64 + col) < (NS_ + P_);
                } else {
                    int i = (ch - 7) * 64 + col;
                    valid = (i < 127) && ((unsigned)(i - rowl) < 64u);
                }
                s[nf][r] = valid ? s[nf][r] * 0.125f : -INFINITY;
            }
        }

        float fct[4];
        #pragma unroll
        for (int r = 0; r < 4; ++r) {
            float cm = fmaxf(fmaxf(s[0][r], s[1][r]), fmaxf(s[2][r], s[3][r]));
            cm = fmaxf(cm, __shfl_xor(cm, 1, 64));
            cm = fmaxf(cm, __shfl_xor(cm, 2, 64));
            cm = fmaxf(cm, __shfl_xor(cm, 4, 64));
            cm = fmaxf(cm, __shfl_xor(cm, 8, 64));
            float nm = fmaxf(m[r], cm);
            fct[r] = __expf(m[r] - nm);
            m[r] = nm;
        }

        float ps[4] = {0.f, 0.f, 0.f, 0.f};
        #pragma unroll
        for (int nf = 0; nf < 4; ++nf) {
            #pragma unroll
            for (int r = 0; r < 4; ++r) {
                float p = __expf(s[nf][r] - m[r]);
                ps[r] += p;
                int rowl = wr + g * 4 + r;
                Pf[rowl][(nf * 16 + c) ^ ((rowl & 7) << 3)] = f16bits(p);
            }
        }
        #pragma unroll
        for (int r = 0; r < 4; ++r) {
            ps[r] += __shfl_xor(ps[r], 1, 64);
            ps[r] += __shfl_xor(ps[r], 2, 64);
            ps[r] += __shfl_xor(ps[r], 4, 64);
            ps[r] += __shfl_xor(ps[r], 8, 64);
            l[r] = l[r] * fct[r] + ps[r];
        }
        #pragma unroll
        for (int nf = 0; nf < 4; ++nf)
            #pragma unroll
            for (int r = 0; r < 4; ++r)
                o[nf][r] *= fct[r];

        f16x8 pa[2];
        {
            int prow = wr + c;
            pa[0] = *(const f16x8*)&Pf[prow][(g * 8) ^ ((prow & 7) << 3)];
            pa[1] = *(const f16x8*)&Pf[prow][(32 + g * 8) ^ ((prow & 7) << 3)];
        }

        #pragma unroll
        for (int ss = 0; ss < 2; ++ss) {
            #pragma unroll
            for (int nf = 0; nf < 4; ++nf) {
                int d = nf * 16 + c;
                int kx = (ss * 32 + g * 8) ^ ((d & 7) << 3);
                f16x8 vf = *(const f16x8*)&Vf[buf][d][kx];
                o[nf] = __builtin_amdgcn_mfma_f32_16x16x32_f16(pa[ss], vf, o[nf], 0, 0, 0);
            }
        }

        if (pre) vwrite(buf ^ 1, vr);
        __syncthreads();
        buf ^= 1;
    }

    unsigned short* pob = po + (size_t)slot * 4096;
    #pragma unroll
    for (int r = 0; r < 4; ++r) {
        int rowl = wr + g * 4 + r;
        if (!is_pano && rowl >= NS_) continue;
        #pragma unroll
        for (int nf = 0; nf < 4; ++nf)
            pob[rowl * 64 + nf * 16 + c] = f16bits(o[nf][r]);
        if (c == 0) {
            pm[(size_t)slot * 64 + rowl] = m[r];
            pl[(size_t)slot * 64 + rowl] = l[r];
        }
    }
}

// ---------------------------------------------------------------------------
// Fused combine -> fp16 att. Blocks [0,336) pano, [336,396) spatial.
// ---------------------------------------------------------------------------
__global__ __launch_bounds__(256)
void attn_comb(const unsigned short* __restrict__ po, const float* __restrict__ pm,
               const float* __restrict__ pl, unsigned short* __restrict__ attf)
{
    const int b = blockIdx.x;
    const int tid = threadIdx.x;
    if (b < 336) {
        const int pt = b % PTILES;
        const int t2 = b / PTILES;
        const int vw = t2 & 3;
        const int h  = t2 >> 2;
        const int d = tid & 63;
        const int rg = tid >> 6;
        const int tb = b * 3;

        for (int i = 0; i < 16; ++i) {
            int row = rg * 16 + i;
            int prow = pt * 64 + row;
            if (prow >= P_) break;
            float m0 = pm[(size_t)tb * 64 + row],       l0 = pl[(size_t)tb * 64 + row];
            float m1 = pm[(size_t)(tb + 1) * 64 + row], l1 = pl[(size_t)(tb + 1) * 64 + row];
            float m2 = pm[(size_t)(tb + 2) * 64 + row], l2 = pl[(size_t)(tb + 2) * 64 + row];
            float M = fmaxf(fmaxf(m0, m1), m2);
            float w0 = __expf(m0 - M), w1 = __expf(m1 - M), w2 = __expf(m2 - M);
            float inv = 1.0f / (l0 * w0 + l1 * w1 + l2 * w2);
            float o0 = f16val(po[(size_t)tb * 4096 + row * 64 + d]);
            float o1 = f16val(po[(size_t)(tb + 1) * 4096 + row * 64 + d]);
            float o2 = f16val(po[(size_t)(tb + 2) * 4096 + row * 64 + d]);
            float oo = (o0 * w0 + o1 * w1 + o2 * w2) * inv;
            size_t idx = ((size_t)(NS_ + vw * P_ + prow)) * C_ + h * 64 + d;
            attf[idx] = f16bits(oo);
        }
    } else {
        const int rid = (b - 336) * 4 + (tid >> 6);   // 0..239
        const int s = rid % NS_;
        const int h = rid / NS_;
        const int d = tid & 63;

        float M = -INFINITY;
        #pragma unroll 2
        for (int sp = 0; sp < SPL; ++sp)
            M = fmaxf(M, pm[(size_t)(NPANO + h * SPL + sp) * 64 + s]);
        float num = 0.f, den = 0.f;
        for (int sp = 0; sp < SPL; ++sp) {
            size_t sl = NPANO + h * SPL + sp;
            float w = __expf(pm[sl * 64 + s] - M);
            den = fmaf(pl[sl * 64 + s], w, den);
            num = fmaf(f16val(po[sl * 4096 + s * 64 + d]), w, num);
        }
        size_t idx = (size_t)s * C_ + h * 64 + d;
        attf[idx] = f16bits(num / den);
    }
}

// ---------------------------------------------------------------------------
extern "C" void kernel_launch(void* const* d_in, const int* in_sizes, int n_in,
                              void* d_out, int out_size, void* d_ws, size_t ws_size,
                              hipStream_t stream)
{
    const float* x       = (const float*)d_in[0];
    const float* qkv_w   = (const float*)d_in[1];
    const float* qkv_b   = (const float*)d_in[2];
    const float* proj_w  = (const float*)d_in[3];
    const float* proj_b  = (const float*)d_in[4];
    float* out = (float*)d_out;

    const size_t per = (size_t)H_ * N_ * D_;
    unsigned short* qph = (unsigned short*)d_ws;       // fp16 q [h][n][d]
    unsigned short* kph = qph + per;
    unsigned short* vph = kph + per;
    unsigned short* xf  = vph + per;                   // fp16 x
    unsigned short* wf  = xf + (size_t)N_ * C_;        // fp16 qkv_w
    unsigned short* pwf = wf + (size_t)3 * C_ * C_;    // fp16 proj_w
    unsigned short* attf = pwf + (size_t)C_ * C_;      // fp16 att
    unsigned short* ppo = attf + (size_t)N_ * C_;      // fp16 partials
    float* ppm = (float*)(ppo + (size_t)NPART * 4096);
    float* ppl = ppm + (size_t)NPART * 64;

    // 0) convert inputs to fp16
    {
        int total = N4_X + N4_W + N4_PW;
        cvt_all<<<(total + 255) / 256, 256, 0, stream>>>(x, qkv_w, proj_w, xf, wf, pwf);
    }

    // 1) QKV projection (fp16 MFMA), fp16 q/k/v scatter
    gemm_f16<1><<<26 * 36, 256, 0, stream>>>(xf, wf, qkv_b, N_, 3 * C_,
                                             (float*)qph, (float*)kph, (float*)vph);

    // 2) unified attention partials (single-fp16 MFMA, dbuf chunks)
    attn_fused<<<NPART, 256, 0, stream>>>(qph, kph, vph, ppo, ppm, ppl);

    // 3) fused combine -> fp16 att
    attn_comb<<<396, 256, 0, stream>>>(ppo, ppm, ppl, attf);

    // 4) output projection (fp16 MFMA), f32 out
    gemm_f16<0><<<26 * 12, 256, 0, stream>>>(attf, pwf, proj_b, N_, C_, out, nullptr, nullptr);
}